// Round 8
// baseline (190.517 us; speedup 1.0000x reference)
//
#include <hip/hip_runtime.h>
#include <hip/hip_bf16.h>
#include <math.h>

#define CDIM 192
#define DD 28
#define NVOX (DD * DD * DD)   // 21952

typedef __attribute__((ext_vector_type(8))) short bf16x8;
typedef __attribute__((ext_vector_type(4))) float f32x4;

__device__ __forceinline__ float blo(unsigned int u) {
  union { unsigned int i; float f; } w; w.i = u << 16; return w.f;
}
__device__ __forceinline__ float bhi(unsigned int u) {
  union { unsigned int i; float f; } w; w.i = u & 0xffff0000u; return w.f;
}
__device__ __forceinline__ unsigned short f2bf(float f) {
  union { float ff; unsigned int i; } w; w.ff = f;
  unsigned int x = w.i;
  return (unsigned short)((x + 0x7fffu + ((x >> 16) & 1u)) >> 16);  // RNE
}
__device__ __forceinline__ unsigned int pk2(float lo, float hi) {
  // packed RNE convert; compiler emits v_cvt_pk_bf16_f32
  __hip_bfloat162 h = __float22bfloat162_rn(make_float2(lo, hi));
  union { __hip_bfloat162 h2; unsigned int u; } cv; cv.h2 = h; return cv.u;
}

// prep: weights -> bf16, transposed to [n][k]; scale folded into Wq/bq.
// WqkvT is [576][192]: rows 0..191 = Wq^T * scale, rows 192..575 = Wkv^T.
__global__ __launch_bounds__(256) void prep_w(
    const float* __restrict__ Wq, const float* __restrict__ Wkv,
    const float* __restrict__ Wp, const float* __restrict__ bq,
    const float* __restrict__ bkv,
    unsigned short* __restrict__ WqkvT, unsigned short* __restrict__ WpT,
    float* __restrict__ biasAll, float scale)
{
  int t = blockIdx.x * 256 + threadIdx.x;
  if (t < 576 * CDIM) {
    const int n = t / CDIM, k = t % CDIM;
    const float v = (n < CDIM) ? Wq[k * CDIM + n] * scale
                               : Wkv[k * 2 * CDIM + (n - CDIM)];
    WqkvT[t] = f2bf(v);
    return;
  }
  t -= 576 * CDIM;
  if (t < CDIM * CDIM) {
    const int n = t / CDIM, k = t % CDIM;
    WpT[t] = f2bf(Wp[k * CDIM + n]);
    return;
  }
  t -= CDIM * CDIM;
  if (t < 576)
    biasAll[t] = (t < CDIM) ? bq[t] * scale : bkv[t - CDIM];
}

// Fused QKV GEMM: [q|k|v] = x @ WqkvT^T + biasAll. Grid (343, 9): each block
// one 64x64 tile, fully parallel. A (fp32) converted to bf16 during staging.
__global__ __launch_bounds__(256) void gemm_qkv(
    const float* __restrict__ X,            // [M][192] fp32
    const unsigned short* __restrict__ Bt,  // [576][192] bf16
    const float* __restrict__ biasAll,      // [576]
    unsigned short* __restrict__ qb,        // [M][192]
    unsigned short* __restrict__ kvb)       // [M][384]
{
  __shared__ unsigned short As[64 * 200];
  __shared__ unsigned short Bs[64 * 200];
  const int tid = threadIdx.x;
  const int m0 = blockIdx.x * 64;
  const int n0 = blockIdx.y * 64;

#pragma unroll
  for (int u = tid; u < 1536; u += 256) {  // 64 rows x 24 8-elem units
    const int row = u / 24, c = (u % 24) * 8;
    const float4 f0 = *(const float4*)(&X[(size_t)(m0 + row) * CDIM + c]);
    const float4 f1 = *(const float4*)(&X[(size_t)(m0 + row) * CDIM + c + 4]);
    unsigned int o[4] = {pk2(f0.x, f0.y), pk2(f0.z, f0.w),
                         pk2(f1.x, f1.y), pk2(f1.z, f1.w)};
    *(uint4*)(&As[row * 200 + c]) = *(const uint4*)o;
    *(uint4*)(&Bs[row * 200 + c]) =
        *(const uint4*)(&Bt[(size_t)(n0 + row) * CDIM + c]);
  }
  __syncthreads();

  const int l = tid & 63, w = tid >> 6;
  const int wm = (w >> 1) * 32, wn = (w & 1) * 32;
  const int lr = l & 15, lk = (l >> 4) * 8;
  const unsigned short* pa = &As[(wm + lr) * 200 + lk];
  const unsigned short* pb = &Bs[(wn + lr) * 200 + lk];

  f32x4 acc[2][2] = {};
#pragma unroll
  for (int k0 = 0; k0 < CDIM; k0 += 32) {
    const bf16x8 a0 = *(const bf16x8*)(pa + k0);
    const bf16x8 a1 = *(const bf16x8*)(pa + 16 * 200 + k0);
    const bf16x8 b0 = *(const bf16x8*)(pb + k0);
    const bf16x8 b1 = *(const bf16x8*)(pb + 16 * 200 + k0);
    acc[0][0] = __builtin_amdgcn_mfma_f32_16x16x32_bf16(a0, b0, acc[0][0], 0, 0, 0);
    acc[0][1] = __builtin_amdgcn_mfma_f32_16x16x32_bf16(a0, b1, acc[0][1], 0, 0, 0);
    acc[1][0] = __builtin_amdgcn_mfma_f32_16x16x32_bf16(a1, b0, acc[1][0], 0, 0, 0);
    acc[1][1] = __builtin_amdgcn_mfma_f32_16x16x32_bf16(a1, b1, acc[1][1], 0, 0, 0);
  }

  // C/D: col = lane&15, row = (lane>>4)*4 + reg
#pragma unroll
  for (int i = 0; i < 2; ++i)
#pragma unroll
    for (int j = 0; j < 2; ++j) {
      const int gc = n0 + wn + j * 16 + lr;
      const float bv = biasAll[gc];
#pragma unroll
      for (int r = 0; r < 4; ++r) {
        const int gr = m0 + wm + i * 16 + (l >> 4) * 4 + r;
        const float v = acc[i][j][r] + bv;
        if (gc < CDIM)
          qb[(size_t)gr * CDIM + gc] = f2bf(v);
        else
          kvb[(size_t)gr * 2 * CDIM + (gc - CDIM)] = f2bf(v);
      }
    }
}

// x-line attention, shuffle-free. One wave per (z,y,head); lane = (x, g);
// lane owns 24 channels. dx=+-1 neighbors are DIRECT loads (same cache
// lines the wave fetches anyway) instead of ds_bpermute chains — DS ops
// per row drop 51 -> 3 (half-head xor only). OOB slots (zero-padded k/v):
// logit 0 stays in denominator -> closed-form init m=0, s=noob.
__global__ __launch_bounds__(256) void attn3d_line(
    const unsigned short* __restrict__ q,
    const unsigned short* __restrict__ kv,
    unsigned short* __restrict__ y)
{
  const int bid = blockIdx.x;
  const int zy = (bid & 7) * 98 + (bid >> 3);   // 784 = 8*98 bijective
  const int z = zy / 28, yr = zy % 28;
  const int h = threadIdx.x >> 6;
  const int lane = threadIdx.x & 63;
  const int x = lane & 31;
  const int xc = x < 28 ? x : 27;               // clamp idle lanes
  const int g = lane >> 5;
  const int cb = h * 48 + g * 24;               // 24 ch = 3 uint4
  const int vox = (z * 28 + yr) * 28 + xc;

  float qf[24];
  {
    const uint4* qp = (const uint4*)(q + (size_t)vox * CDIM + cb);
    const uint4 a = qp[0], b = qp[1], c = qp[2];
    const unsigned int uu[12] = {a.x, a.y, a.z, a.w, b.x, b.y, b.z, b.w,
                                 c.x, c.y, c.z, c.w};
#pragma unroll
    for (int i = 0; i < 12; ++i) { qf[2*i] = blo(uu[i]); qf[2*i+1] = bhi(uu[i]); }
  }

  const int nx = 3 - (x == 0) - (x == 27);
  const int nyv = 3 - (yr == 0) - (yr == 27);
  const int nzv = 3 - (z == 0) - (z == 27);
  const int noob = 27 - nx * nyv * nzv;
  float m = noob ? 0.f : -INFINITY;
  float s = (float)noob;
  float out[24];
#pragma unroll
  for (int i = 0; i < 24; ++i) out[i] = 0.f;

  const bool okm = (x > 0), okp = (x < 27);
  const int xm = okm ? xc - 1 : 0;
  const int xp = okp ? xc + 1 : 27;
  // element offsets within a (z,y) row for the three x-slices
  const size_t om = (size_t)xm * 384 + cb;
  const size_t oc = (size_t)xc * 384 + cb;
  const size_t op = (size_t)xp * 384 + cb;

  for (int dz = -1; dz <= 1; ++dz) {
    const int zz = z + dz;
    if ((unsigned)zz >= 28u) continue;          // block-uniform
    for (int dy = -1; dy <= 1; ++dy) {
      const int yv = yr + dy;
      if ((unsigned)yv >= 28u) continue;        // block-uniform
      const unsigned short* rp = kv + (size_t)((zz * 28 + yv) * 28) * 384;

      const uint4* kmp = (const uint4*)(rp + om);
      const uint4* kcp = (const uint4*)(rp + oc);
      const uint4* kpp = (const uint4*)(rp + op);
      const uint4 Km0 = kmp[0], Km1 = kmp[1], Km2 = kmp[2];
      const uint4 Kc0 = kcp[0], Kc1 = kcp[1], Kc2 = kcp[2];
      const uint4 Kp0 = kpp[0], Kp1 = kpp[1], Kp2 = kpp[2];
      // v slices issued early; consumed after softmax (latency overlap)
      const uint4* vmp = (const uint4*)(rp + om + CDIM);
      const uint4* vcp = (const uint4*)(rp + oc + CDIM);
      const uint4* vpp = (const uint4*)(rp + op + CDIM);
      const uint4 Vm0 = vmp[0], Vm1 = vmp[1], Vm2 = vmp[2];
      const uint4 Vc0 = vcp[0], Vc1 = vcp[1], Vc2 = vcp[2];
      const uint4 Vp0 = vpp[0], Vp1 = vpp[1], Vp2 = vpp[2];

      const unsigned int km[12] = {Km0.x, Km0.y, Km0.z, Km0.w, Km1.x, Km1.y,
                                   Km1.z, Km1.w, Km2.x, Km2.y, Km2.z, Km2.w};
      const unsigned int kc[12] = {Kc0.x, Kc0.y, Kc0.z, Kc0.w, Kc1.x, Kc1.y,
                                   Kc1.z, Kc1.w, Kc2.x, Kc2.y, Kc2.z, Kc2.w};
      const unsigned int kp[12] = {Kp0.x, Kp0.y, Kp0.z, Kp0.w, Kp1.x, Kp1.y,
                                   Kp1.z, Kp1.w, Kp2.x, Kp2.y, Kp2.z, Kp2.w};
      float p0 = 0.f, p1 = 0.f, p2 = 0.f;
#pragma unroll
      for (int i = 0; i < 12; ++i) {
        p0 += qf[2*i] * blo(km[i]) + qf[2*i+1] * bhi(km[i]);
        p1 += qf[2*i] * blo(kc[i]) + qf[2*i+1] * bhi(kc[i]);
        p2 += qf[2*i] * blo(kp[i]) + qf[2*i+1] * bhi(kp[i]);
      }
      p0 += __shfl_xor(p0, 32);   // combine half-head partials
      p1 += __shfl_xor(p1, 32);
      p2 += __shfl_xor(p2, 32);

      const float l0 = okm ? p0 : -INFINITY;
      const float l2 = okp ? p2 : -INFINITY;
      const float nm = fmaxf(m, fmaxf(p1, fmaxf(l0, l2)));
      const float sc = __expf(m - nm);
      const float w0 = okm ? __expf(p0 - nm) : 0.f;
      const float w1 = __expf(p1 - nm);
      const float w2 = okp ? __expf(p2 - nm) : 0.f;
      s = s * sc + w0 + w1 + w2;
      m = nm;

      const unsigned int vm[12] = {Vm0.x, Vm0.y, Vm0.z, Vm0.w, Vm1.x, Vm1.y,
                                   Vm1.z, Vm1.w, Vm2.x, Vm2.y, Vm2.z, Vm2.w};
      const unsigned int vc[12] = {Vc0.x, Vc0.y, Vc0.z, Vc0.w, Vc1.x, Vc1.y,
                                   Vc1.z, Vc1.w, Vc2.x, Vc2.y, Vc2.z, Vc2.w};
      const unsigned int vp[12] = {Vp0.x, Vp0.y, Vp0.z, Vp0.w, Vp1.x, Vp1.y,
                                   Vp1.z, Vp1.w, Vp2.x, Vp2.y, Vp2.z, Vp2.w};
#pragma unroll
      for (int i = 0; i < 12; ++i) {
        out[2*i]   = out[2*i]   * sc + w0 * blo(vm[i]) + w1 * blo(vc[i]) + w2 * blo(vp[i]);
        out[2*i+1] = out[2*i+1] * sc + w0 * bhi(vm[i]) + w1 * bhi(vc[i]) + w2 * bhi(vp[i]);
      }
    }
  }

  if (x < 28) {
    const float inv = 1.f / s;
    unsigned int ou[12];
#pragma unroll
    for (int i = 0; i < 12; ++i)
      ou[i] = (unsigned int)f2bf(out[2*i] * inv) |
              ((unsigned int)f2bf(out[2*i+1] * inv) << 16);
    uint4* yp = (uint4*)(y + (size_t)vox * CDIM + cb);
    yp[0] = make_uint4(ou[0], ou[1], ou[2], ou[3]);
    yp[1] = make_uint4(ou[4], ou[5], ou[6], ou[7]);
    yp[2] = make_uint4(ou[8], ou[9], ou[10], ou[11]);
  }
}

// Output projection: out = y @ WpT^T + bp, fp32 out. 64x64 tiles, grid (3,343).
__global__ __launch_bounds__(256) void gemm_out(
    const unsigned short* __restrict__ A,
    const unsigned short* __restrict__ Bt,
    const float* __restrict__ bias,
    float* __restrict__ C)
{
  __shared__ unsigned short As[64 * 200];
  __shared__ unsigned short Bs[64 * 200];
  const int tid = threadIdx.x;
  const int n0 = blockIdx.x * 64;
  const int m0 = blockIdx.y * 64;

#pragma unroll
  for (int u = tid; u < 1536; u += 256) {
    const int row = u / 24, c = (u % 24) * 8;
    *(uint4*)(&As[row * 200 + c]) =
        *(const uint4*)(&A[(size_t)(m0 + row) * CDIM + c]);
    *(uint4*)(&Bs[row * 200 + c]) =
        *(const uint4*)(&Bt[(size_t)(n0 + row) * CDIM + c]);
  }
  __syncthreads();

  const int l = tid & 63, w = tid >> 6;
  const int wm = (w >> 1) * 32, wn = (w & 1) * 32;
  const int lr = l & 15, lk = (l >> 4) * 8;

  f32x4 acc[2][2] = {};
  const unsigned short* pa = &As[(wm + lr) * 200 + lk];
  const unsigned short* pb = &Bs[(wn + lr) * 200 + lk];

#pragma unroll
  for (int k0 = 0; k0 < CDIM; k0 += 32) {
    const bf16x8 a0 = *(const bf16x8*)(pa + k0);
    const bf16x8 a1 = *(const bf16x8*)(pa + 16 * 200 + k0);
    const bf16x8 b0 = *(const bf16x8*)(pb + k0);
    const bf16x8 b1 = *(const bf16x8*)(pb + 16 * 200 + k0);
    acc[0][0] = __builtin_amdgcn_mfma_f32_16x16x32_bf16(a0, b0, acc[0][0], 0, 0, 0);
    acc[0][1] = __builtin_amdgcn_mfma_f32_16x16x32_bf16(a0, b1, acc[0][1], 0, 0, 0);
    acc[1][0] = __builtin_amdgcn_mfma_f32_16x16x32_bf16(a1, b0, acc[1][0], 0, 0, 0);
    acc[1][1] = __builtin_amdgcn_mfma_f32_16x16x32_bf16(a1, b1, acc[1][1], 0, 0, 0);
  }

#pragma unroll
  for (int i = 0; i < 2; ++i)
#pragma unroll
    for (int j = 0; j < 2; ++j) {
      const int gc = n0 + wn + j * 16 + lr;
      const float bv = bias[gc];
#pragma unroll
      for (int r = 0; r < 4; ++r) {
        const int gr = m0 + wm + i * 16 + (l >> 4) * 4 + r;
        C[(size_t)gr * CDIM + gc] = acc[i][j][r] + bv;
      }
    }
}

extern "C" void kernel_launch(void* const* d_in, const int* in_sizes, int n_in,
                              void* d_out, int out_size, void* d_ws, size_t ws_size,
                              hipStream_t stream) {
  const float* x   = (const float*)d_in[0];
  const float* Wq  = (const float*)d_in[1];
  const float* bq  = (const float*)d_in[2];
  const float* Wkv = (const float*)d_in[3];
  const float* bkv = (const float*)d_in[4];
  const float* Wp  = (const float*)d_in[5];
  const float* bp  = (const float*)d_in[6];
  float* out = (float*)d_out;

  unsigned short* WqkvT = (unsigned short*)d_ws;          // 576*192
  unsigned short* WpT   = WqkvT + 576 * CDIM;             // 192*192
  float*          biasA = (float*)(WpT + CDIM * CDIM);    // 576 floats
  unsigned short* qb    = (unsigned short*)(biasA + 576); // NVOX*192
  unsigned short* kvb   = qb + (size_t)NVOX * CDIM;       // NVOX*384
  unsigned short* yb    = kvb + (size_t)NVOX * 2 * CDIM;  // NVOX*192

  const float scale = 1.0f / sqrtf(48.0f);

  // prep threads: 576*192 + 192*192 + 576 = 148032
  prep_w<<<(148032 + 255) / 256, 256, 0, stream>>>(
      Wq, Wkv, Wp, bq, bkv, WqkvT, WpT, biasA, scale);

  gemm_qkv<<<dim3(NVOX / 64, 9), 256, 0, stream>>>(x, WqkvT, biasA, qb, kvb);
  attn3d_line<<<DD * DD, 256, 0, stream>>>(qb, kvb, yb);
  gemm_out<<<dim3(3, NVOX / 64), 256, 0, stream>>>(yb, WpT, bp, out);
}

// Round 9
// 188.185 us; speedup vs baseline: 1.0124x; 1.0124x over previous
//
#include <hip/hip_runtime.h>
#include <hip/hip_bf16.h>
#include <math.h>

#define CDIM 192
#define DD 28
#define NVOX (DD * DD * DD)   // 21952

typedef __attribute__((ext_vector_type(8))) short bf16x8;
typedef __attribute__((ext_vector_type(4))) float f32x4;

__device__ __forceinline__ float blo(unsigned int u) {
  union { unsigned int i; float f; } w; w.i = u << 16; return w.f;
}
__device__ __forceinline__ float bhi(unsigned int u) {
  union { unsigned int i; float f; } w; w.i = u & 0xffff0000u; return w.f;
}
__device__ __forceinline__ unsigned short f2bf(float f) {
  union { float ff; unsigned int i; } w; w.ff = f;
  unsigned int x = w.i;
  return (unsigned short)((x + 0x7fffu + ((x >> 16) & 1u)) >> 16);  // RNE
}
__device__ __forceinline__ unsigned int pk2(float lo, float hi) {
  __hip_bfloat162 h = __float22bfloat162_rn(make_float2(lo, hi));
  union { __hip_bfloat162 h2; unsigned int u; } cv; cv.h2 = h; return cv.u;
}

// prep: weights -> bf16, transposed to [n][k]; scale folded into Wq/bq.
__global__ __launch_bounds__(256) void prep_w(
    const float* __restrict__ Wq, const float* __restrict__ Wkv,
    const float* __restrict__ Wp, const float* __restrict__ bq,
    const float* __restrict__ bkv,
    unsigned short* __restrict__ WqkvT, unsigned short* __restrict__ WpT,
    float* __restrict__ biasAll, float scale)
{
  int t = blockIdx.x * 256 + threadIdx.x;
  if (t < 576 * CDIM) {
    const int n = t / CDIM, k = t % CDIM;
    const float v = (n < CDIM) ? Wq[k * CDIM + n] * scale
                               : Wkv[k * 2 * CDIM + (n - CDIM)];
    WqkvT[t] = f2bf(v);
    return;
  }
  t -= 576 * CDIM;
  if (t < CDIM * CDIM) {
    const int n = t / CDIM, k = t % CDIM;
    WpT[t] = f2bf(Wp[k * CDIM + n]);
    return;
  }
  t -= CDIM * CDIM;
  if (t < 576)
    biasAll[t] = (t < CDIM) ? bq[t] * scale : bkv[t - CDIM];
}

// Fused QKV GEMM: [q|k|v] = x @ WqkvT^T + biasAll. Grid (343, 3): each block
// stages its fp32->bf16 A-tile ONCE and serially does 3 column tiles
// (by, by+3, by+6) — A-traffic 3x lower than the (343,9) grid.
__global__ __launch_bounds__(256) void gemm_qkv(
    const float* __restrict__ X,            // [M][192] fp32
    const unsigned short* __restrict__ Bt,  // [576][192] bf16
    const float* __restrict__ biasAll,      // [576]
    unsigned short* __restrict__ qb,        // [M][192]
    unsigned short* __restrict__ kvb)       // [M][384]
{
  __shared__ unsigned short As[64 * 200];
  __shared__ unsigned short Bs[64 * 200];
  const int tid = threadIdx.x;
  const int m0 = blockIdx.x * 64;
  const int by = blockIdx.y;

#pragma unroll
  for (int u = tid; u < 1536; u += 256) {  // 64 rows x 24 8-elem units
    const int row = u / 24, c = (u % 24) * 8;
    const float4 f0 = *(const float4*)(&X[(size_t)(m0 + row) * CDIM + c]);
    const float4 f1 = *(const float4*)(&X[(size_t)(m0 + row) * CDIM + c + 4]);
    unsigned int o[4] = {pk2(f0.x, f0.y), pk2(f0.z, f0.w),
                         pk2(f1.x, f1.y), pk2(f1.z, f1.w)};
    *(uint4*)(&As[row * 200 + c]) = *(const uint4*)o;
  }

  const int l = tid & 63, w = tid >> 6;
  const int wm = (w >> 1) * 32, wn = (w & 1) * 32;
  const int lr = l & 15, lk = (l >> 4) * 8;
  const unsigned short* pa = &As[(wm + lr) * 200 + lk];
  const unsigned short* pb = &Bs[(wn + lr) * 200 + lk];

  for (int nt = by; nt < 9; nt += 3) {
    const int n0 = nt * 64;
    __syncthreads();  // iter 0: As ready; later: prev Bs readers done
#pragma unroll
    for (int u = tid; u < 1536; u += 256) {
      const int row = u / 24, c = (u % 24) * 8;
      *(uint4*)(&Bs[row * 200 + c]) =
          *(const uint4*)(&Bt[(size_t)(n0 + row) * CDIM + c]);
    }
    __syncthreads();

    f32x4 acc[2][2] = {};
#pragma unroll
    for (int k0 = 0; k0 < CDIM; k0 += 32) {
      const bf16x8 a0 = *(const bf16x8*)(pa + k0);
      const bf16x8 a1 = *(const bf16x8*)(pa + 16 * 200 + k0);
      const bf16x8 b0 = *(const bf16x8*)(pb + k0);
      const bf16x8 b1 = *(const bf16x8*)(pb + 16 * 200 + k0);
      acc[0][0] = __builtin_amdgcn_mfma_f32_16x16x32_bf16(a0, b0, acc[0][0], 0, 0, 0);
      acc[0][1] = __builtin_amdgcn_mfma_f32_16x16x32_bf16(a0, b1, acc[0][1], 0, 0, 0);
      acc[1][0] = __builtin_amdgcn_mfma_f32_16x16x32_bf16(a1, b0, acc[1][0], 0, 0, 0);
      acc[1][1] = __builtin_amdgcn_mfma_f32_16x16x32_bf16(a1, b1, acc[1][1], 0, 0, 0);
    }

    // C/D: col = lane&15, row = (lane>>4)*4 + reg
#pragma unroll
    for (int i = 0; i < 2; ++i)
#pragma unroll
      for (int j = 0; j < 2; ++j) {
        const int gc = n0 + wn + j * 16 + lr;
        const float bv = biasAll[gc];
#pragma unroll
        for (int r = 0; r < 4; ++r) {
          const int gr = m0 + wm + i * 16 + (l >> 4) * 4 + r;
          const float v = acc[i][j][r] + bv;
          if (gc < CDIM)
            qb[(size_t)gr * CDIM + gc] = f2bf(v);
          else
            kvb[(size_t)gr * 2 * CDIM + (gc - CDIM)] = f2bf(v);
        }
      }
  }
}

// x-line attention, split-row waves. Block = (z,y), 8 waves: head = w>>1,
// part = w&1 (part0: rows 0..4 of the 9 (dz,dy) rows incl. center, part1:
// rows 5..8). Lane = (x, half-head g); lane owns 24 ch. Direct loads of the
// x-1/x/x+1 slices (K phase then V phase to cap live registers). Partial
// online-softmax states merge via LDS. OOB slots (zero-padded k/v): logit 0
// in denominator -> part0 init m=0, s=noob; part1 init m=-inf, s=0.
__global__ __launch_bounds__(512, 4) void attn3d_line(
    const unsigned short* __restrict__ q,
    const unsigned short* __restrict__ kv,
    unsigned short* __restrict__ y)
{
  __shared__ float sm_m[4][64];
  __shared__ float sm_s[4][64];
  __shared__ __align__(16) float sm_o[4][64][24];

  const int bid = blockIdx.x;
  const int zy = (bid & 7) * 98 + (bid >> 3);   // 784 = 8*98 bijective
  const int z = zy / 28, yr = zy % 28;
  const int wv = threadIdx.x >> 6;
  const int h = wv >> 1;
  const int p = wv & 1;
  const int lane = threadIdx.x & 63;
  const int x = lane & 31;
  const int xc = x < 28 ? x : 27;               // clamp idle lanes
  const int g = lane >> 5;
  const int cb = h * 48 + g * 24;               // 24 ch = 3 uint4
  const int vox = (z * 28 + yr) * 28 + xc;

  float qf[24];
  {
    const uint4* qp = (const uint4*)(q + (size_t)vox * CDIM + cb);
    const uint4 a = qp[0], b = qp[1], c = qp[2];
    const unsigned int uu[12] = {a.x, a.y, a.z, a.w, b.x, b.y, b.z, b.w,
                                 c.x, c.y, c.z, c.w};
#pragma unroll
    for (int i = 0; i < 12; ++i) { qf[2*i] = blo(uu[i]); qf[2*i+1] = bhi(uu[i]); }
  }

  float m, s;
  if (p == 0) {
    const int nx = 3 - (x == 0) - (x == 27);
    const int ny = 3 - (yr == 0) - (yr == 27);
    const int nz = 3 - (z == 0) - (z == 27);
    const int noob = 27 - nx * ny * nz;
    m = noob ? 0.f : -INFINITY;
    s = (float)noob;
  } else { m = -INFINITY; s = 0.f; }
  float out[24];
#pragma unroll
  for (int i = 0; i < 24; ++i) out[i] = 0.f;

  const bool okm = (x > 0), okp = (x < 27);
  const int xm = okm ? xc - 1 : 0;
  const int xp = okp ? xc + 1 : 27;
  const size_t om = (size_t)xm * 384 + cb;
  const size_t oc = (size_t)xc * 384 + cb;
  const size_t op = (size_t)xp * 384 + cb;

  const int rbeg = p ? 5 : 0, rend = p ? 9 : 5;
  for (int r = rbeg; r < rend; ++r) {
    const int zz = z + r / 3 - 1, yv = yr + r % 3 - 1;
    if ((unsigned)zz >= 28u) continue;          // wave-uniform
    if ((unsigned)yv >= 28u) continue;          // wave-uniform
    const unsigned short* rp = kv + (size_t)((zz * 28 + yv) * 28) * 384;

    // ---- K phase ----
    const uint4* kmp = (const uint4*)(rp + om);
    const uint4* kcp = (const uint4*)(rp + oc);
    const uint4* kpp = (const uint4*)(rp + op);
    const uint4 Km0 = kmp[0], Km1 = kmp[1], Km2 = kmp[2];
    const uint4 Kc0 = kcp[0], Kc1 = kcp[1], Kc2 = kcp[2];
    const uint4 Kp0 = kpp[0], Kp1 = kpp[1], Kp2 = kpp[2];
    const unsigned int km[12] = {Km0.x, Km0.y, Km0.z, Km0.w, Km1.x, Km1.y,
                                 Km1.z, Km1.w, Km2.x, Km2.y, Km2.z, Km2.w};
    const unsigned int kc[12] = {Kc0.x, Kc0.y, Kc0.z, Kc0.w, Kc1.x, Kc1.y,
                                 Kc1.z, Kc1.w, Kc2.x, Kc2.y, Kc2.z, Kc2.w};
    const unsigned int kp[12] = {Kp0.x, Kp0.y, Kp0.z, Kp0.w, Kp1.x, Kp1.y,
                                 Kp1.z, Kp1.w, Kp2.x, Kp2.y, Kp2.z, Kp2.w};
    float p0 = 0.f, p1 = 0.f, p2 = 0.f;
#pragma unroll
    for (int i = 0; i < 12; ++i) {
      p0 += qf[2*i] * blo(km[i]) + qf[2*i+1] * bhi(km[i]);
      p1 += qf[2*i] * blo(kc[i]) + qf[2*i+1] * bhi(kc[i]);
      p2 += qf[2*i] * blo(kp[i]) + qf[2*i+1] * bhi(kp[i]);
    }
    p0 += __shfl_xor(p0, 32);   // combine half-head partials
    p1 += __shfl_xor(p1, 32);
    p2 += __shfl_xor(p2, 32);

    const float l0 = okm ? p0 : -INFINITY;
    const float l2 = okp ? p2 : -INFINITY;
    const float nm = fmaxf(m, fmaxf(p1, fmaxf(l0, l2)));
    const float sc = __expf(m - nm);
    const float w0 = okm ? __expf(p0 - nm) : 0.f;
    const float w1 = __expf(p1 - nm);
    const float w2 = okp ? __expf(p2 - nm) : 0.f;
    s = s * sc + w0 + w1 + w2;
    m = nm;

    // ---- V phase ----
    const uint4* vmp = (const uint4*)(rp + om + CDIM);
    const uint4* vcp = (const uint4*)(rp + oc + CDIM);
    const uint4* vpp = (const uint4*)(rp + op + CDIM);
    const uint4 Vm0 = vmp[0], Vm1 = vmp[1], Vm2 = vmp[2];
    const uint4 Vc0 = vcp[0], Vc1 = vcp[1], Vc2 = vcp[2];
    const uint4 Vp0 = vpp[0], Vp1 = vpp[1], Vp2 = vpp[2];
    const unsigned int vm[12] = {Vm0.x, Vm0.y, Vm0.z, Vm0.w, Vm1.x, Vm1.y,
                                 Vm1.z, Vm1.w, Vm2.x, Vm2.y, Vm2.z, Vm2.w};
    const unsigned int vc[12] = {Vc0.x, Vc0.y, Vc0.z, Vc0.w, Vc1.x, Vc1.y,
                                 Vc1.z, Vc1.w, Vc2.x, Vc2.y, Vc2.z, Vc2.w};
    const unsigned int vp[12] = {Vp0.x, Vp0.y, Vp0.z, Vp0.w, Vp1.x, Vp1.y,
                                 Vp1.z, Vp1.w, Vp2.x, Vp2.y, Vp2.z, Vp2.w};
#pragma unroll
    for (int i = 0; i < 12; ++i) {
      out[2*i]   = out[2*i]   * sc + w0 * blo(vm[i]) + w1 * blo(vc[i]) + w2 * blo(vp[i]);
      out[2*i+1] = out[2*i+1] * sc + w0 * bhi(vm[i]) + w1 * bhi(vc[i]) + w2 * bhi(vp[i]);
    }
  }

  // ---- merge the two parts via LDS ----
  if (p == 1) {
    sm_m[h][lane] = m;
    sm_s[h][lane] = s;
    float4* o4 = (float4*)sm_o[h][lane];
#pragma unroll
    for (int i = 0; i < 6; ++i)
      o4[i] = make_float4(out[4*i], out[4*i+1], out[4*i+2], out[4*i+3]);
  }
  __syncthreads();
  if (p == 0 && x < 28) {
    const float mb = sm_m[h][lane];
    const float sb = sm_s[h][lane];
    const float nm = fmaxf(m, mb);       // m finite (center row in part0)
    const float wa = __expf(m - nm);
    const float wb = __expf(mb - nm);    // exp(-inf)=0 if part1 empty
    const float inv = 1.f / (s * wa + sb * wb);
    const float* ob = sm_o[h][lane];
    unsigned int ou[12];
#pragma unroll
    for (int i = 0; i < 12; ++i) {
      const float e0 = (out[2*i]   * wa + ob[2*i]   * wb) * inv;
      const float e1 = (out[2*i+1] * wa + ob[2*i+1] * wb) * inv;
      ou[i] = pk2(e0, e1);
    }
    uint4* yp = (uint4*)(y + (size_t)vox * CDIM + cb);
    yp[0] = make_uint4(ou[0], ou[1], ou[2], ou[3]);
    yp[1] = make_uint4(ou[4], ou[5], ou[6], ou[7]);
    yp[2] = make_uint4(ou[8], ou[9], ou[10], ou[11]);
  }
}

// Output projection: out = y @ WpT^T + bp, fp32 out. 64x64 tiles, grid (3,343).
__global__ __launch_bounds__(256) void gemm_out(
    const unsigned short* __restrict__ A,
    const unsigned short* __restrict__ Bt,
    const float* __restrict__ bias,
    float* __restrict__ C)
{
  __shared__ unsigned short As[64 * 200];
  __shared__ unsigned short Bs[64 * 200];
  const int tid = threadIdx.x;
  const int n0 = blockIdx.x * 64;
  const int m0 = blockIdx.y * 64;

#pragma unroll
  for (int u = tid; u < 1536; u += 256) {
    const int row = u / 24, c = (u % 24) * 8;
    *(uint4*)(&As[row * 200 + c]) =
        *(const uint4*)(&A[(size_t)(m0 + row) * CDIM + c]);
    *(uint4*)(&Bs[row * 200 + c]) =
        *(const uint4*)(&Bt[(size_t)(n0 + row) * CDIM + c]);
  }
  __syncthreads();

  const int l = tid & 63, w = tid >> 6;
  const int wm = (w >> 1) * 32, wn = (w & 1) * 32;
  const int lr = l & 15, lk = (l >> 4) * 8;

  f32x4 acc[2][2] = {};
  const unsigned short* pa = &As[(wm + lr) * 200 + lk];
  const unsigned short* pb = &Bs[(wn + lr) * 200 + lk];

#pragma unroll
  for (int k0 = 0; k0 < CDIM; k0 += 32) {
    const bf16x8 a0 = *(const bf16x8*)(pa + k0);
    const bf16x8 a1 = *(const bf16x8*)(pa + 16 * 200 + k0);
    const bf16x8 b0 = *(const bf16x8*)(pb + k0);
    const bf16x8 b1 = *(const bf16x8*)(pb + 16 * 200 + k0);
    acc[0][0] = __builtin_amdgcn_mfma_f32_16x16x32_bf16(a0, b0, acc[0][0], 0, 0, 0);
    acc[0][1] = __builtin_amdgcn_mfma_f32_16x16x32_bf16(a0, b1, acc[0][1], 0, 0, 0);
    acc[1][0] = __builtin_amdgcn_mfma_f32_16x16x32_bf16(a1, b0, acc[1][0], 0, 0, 0);
    acc[1][1] = __builtin_amdgcn_mfma_f32_16x16x32_bf16(a1, b1, acc[1][1], 0, 0, 0);
  }

#pragma unroll
  for (int i = 0; i < 2; ++i)
#pragma unroll
    for (int j = 0; j < 2; ++j) {
      const int gc = n0 + wn + j * 16 + lr;
      const float bv = bias[gc];
#pragma unroll
      for (int r = 0; r < 4; ++r) {
        const int gr = m0 + wm + i * 16 + (l >> 4) * 4 + r;
        C[(size_t)gr * CDIM + gc] = acc[i][j][r] + bv;
      }
    }
}

extern "C" void kernel_launch(void* const* d_in, const int* in_sizes, int n_in,
                              void* d_out, int out_size, void* d_ws, size_t ws_size,
                              hipStream_t stream) {
  const float* x   = (const float*)d_in[0];
  const float* Wq  = (const float*)d_in[1];
  const float* bq  = (const float*)d_in[2];
  const float* Wkv = (const float*)d_in[3];
  const float* bkv = (const float*)d_in[4];
  const float* Wp  = (const float*)d_in[5];
  const float* bp  = (const float*)d_in[6];
  float* out = (float*)d_out;

  unsigned short* WqkvT = (unsigned short*)d_ws;          // 576*192
  unsigned short* WpT   = WqkvT + 576 * CDIM;             // 192*192
  float*          biasA = (float*)(WpT + CDIM * CDIM);    // 576 floats
  unsigned short* qb    = (unsigned short*)(biasA + 576); // NVOX*192
  unsigned short* kvb   = qb + (size_t)NVOX * CDIM;       // NVOX*384
  unsigned short* yb    = kvb + (size_t)NVOX * 2 * CDIM;  // NVOX*192

  const float scale = 1.0f / sqrtf(48.0f);

  // prep threads: 576*192 + 192*192 + 576 = 148032
  prep_w<<<(148032 + 255) / 256, 256, 0, stream>>>(
      Wq, Wkv, Wp, bq, bkv, WqkvT, WpT, biasA, scale);

  gemm_qkv<<<dim3(NVOX / 64, 3), 256, 0, stream>>>(x, WqkvT, biasA, qb, kvb);
  attn3d_line<<<DD * DD, 512, 0, stream>>>(qb, kvb, yb);
  gemm_out<<<dim3(3, NVOX / 64), 256, 0, stream>>>(yb, WpT, bp, out);
}

// Round 10
// 146.794 us; speedup vs baseline: 1.2979x; 1.2820x over previous
//
#include <hip/hip_runtime.h>
#include <hip/hip_bf16.h>
#include <math.h>

#define CDIM 192
#define DD 28
#define NVOX (DD * DD * DD)   // 21952
#define NLINE (DD * DD)       // 784
#define LSTRIDE (24 * DD * 8) // 5376 ushorts per line (24 cg x 28 x x 8ch)

typedef __attribute__((ext_vector_type(8))) short bf16x8;
typedef __attribute__((ext_vector_type(4))) float f32x4;

__device__ __forceinline__ float blo(unsigned int u) {
  union { unsigned int i; float f; } w; w.i = u << 16; return w.f;
}
__device__ __forceinline__ float bhi(unsigned int u) {
  union { unsigned int i; float f; } w; w.i = u & 0xffff0000u; return w.f;
}
__device__ __forceinline__ unsigned short f2bf(float f) {
  union { float ff; unsigned int i; } w; w.ff = f;
  unsigned int x = w.i;
  return (unsigned short)((x + 0x7fffu + ((x >> 16) & 1u)) >> 16);  // RNE
}
__device__ __forceinline__ unsigned int pk2(float lo, float hi) {
  __hip_bfloat162 h = __float22bfloat162_rn(make_float2(lo, hi));
  union { __hip_bfloat162 h2; unsigned int u; } cv; cv.h2 = h; return cv.u;
}

// prep: weights -> bf16, transposed to [n][k]; scale folded into Wq/bq.
__global__ __launch_bounds__(256) void prep_w(
    const float* __restrict__ Wq, const float* __restrict__ Wkv,
    const float* __restrict__ Wp, const float* __restrict__ bq,
    const float* __restrict__ bkv,
    unsigned short* __restrict__ WqkvT, unsigned short* __restrict__ WpT,
    float* __restrict__ biasAll, float scale)
{
  int t = blockIdx.x * 256 + threadIdx.x;
  if (t < 576 * CDIM) {
    const int n = t / CDIM, k = t % CDIM;
    const float v = (n < CDIM) ? Wq[k * CDIM + n] * scale
                               : Wkv[k * 2 * CDIM + (n - CDIM)];
    WqkvT[t] = f2bf(v);
    return;
  }
  t -= 576 * CDIM;
  if (t < CDIM * CDIM) {
    const int n = t / CDIM, k = t % CDIM;
    WpT[t] = f2bf(Wp[k * CDIM + n]);
    return;
  }
  t -= CDIM * CDIM;
  if (t < 576)
    biasAll[t] = (t < CDIM) ? bq[t] * scale : bkv[t - CDIM];
}

// Fused QKV GEMM. q -> vox-major [vox][192]; k,v -> x-interleaved
// [line][cg][x][8ch] so attention slice-loads are lane-coalesced.
__global__ __launch_bounds__(256) void gemm_qkv(
    const float* __restrict__ X,            // [M][192] fp32
    const unsigned short* __restrict__ Bt,  // [576][192] bf16
    const float* __restrict__ biasAll,      // [576]
    unsigned short* __restrict__ qb,        // [vox][192]
    unsigned short* __restrict__ kxb,       // [784][24][28][8]
    unsigned short* __restrict__ vxb)       // [784][24][28][8]
{
  __shared__ unsigned short As[64 * 200];
  __shared__ unsigned short Bs[64 * 200];
  const int tid = threadIdx.x;
  const int m0 = blockIdx.x * 64;
  const int by = blockIdx.y;

#pragma unroll
  for (int u = tid; u < 1536; u += 256) {  // 64 rows x 24 8-elem units
    const int row = u / 24, c = (u % 24) * 8;
    const float4 f0 = *(const float4*)(&X[(size_t)(m0 + row) * CDIM + c]);
    const float4 f1 = *(const float4*)(&X[(size_t)(m0 + row) * CDIM + c + 4]);
    unsigned int o[4] = {pk2(f0.x, f0.y), pk2(f0.z, f0.w),
                         pk2(f1.x, f1.y), pk2(f1.z, f1.w)};
    *(uint4*)(&As[row * 200 + c]) = *(const uint4*)o;
  }

  const int l = tid & 63, w = tid >> 6;
  const int wm = (w >> 1) * 32, wn = (w & 1) * 32;
  const int lr = l & 15, lk = (l >> 4) * 8;
  const unsigned short* pa = &As[(wm + lr) * 200 + lk];
  const unsigned short* pb = &Bs[(wn + lr) * 200 + lk];

  for (int nt = by; nt < 9; nt += 3) {
    const int n0 = nt * 64;
    __syncthreads();  // iter 0: As ready; later: prev Bs readers done
#pragma unroll
    for (int u = tid; u < 1536; u += 256) {
      const int row = u / 24, c = (u % 24) * 8;
      *(uint4*)(&Bs[row * 200 + c]) =
          *(const uint4*)(&Bt[(size_t)(n0 + row) * CDIM + c]);
    }
    __syncthreads();

    f32x4 acc[2][2] = {};
#pragma unroll
    for (int k0 = 0; k0 < CDIM; k0 += 32) {
      const bf16x8 a0 = *(const bf16x8*)(pa + k0);
      const bf16x8 a1 = *(const bf16x8*)(pa + 16 * 200 + k0);
      const bf16x8 b0 = *(const bf16x8*)(pb + k0);
      const bf16x8 b1 = *(const bf16x8*)(pb + 16 * 200 + k0);
      acc[0][0] = __builtin_amdgcn_mfma_f32_16x16x32_bf16(a0, b0, acc[0][0], 0, 0, 0);
      acc[0][1] = __builtin_amdgcn_mfma_f32_16x16x32_bf16(a0, b1, acc[0][1], 0, 0, 0);
      acc[1][0] = __builtin_amdgcn_mfma_f32_16x16x32_bf16(a1, b0, acc[1][0], 0, 0, 0);
      acc[1][1] = __builtin_amdgcn_mfma_f32_16x16x32_bf16(a1, b1, acc[1][1], 0, 0, 0);
    }

    // C/D: col = lane&15, row = (lane>>4)*4 + reg
#pragma unroll
    for (int i = 0; i < 2; ++i)
#pragma unroll
      for (int j = 0; j < 2; ++j) {
        const int gc = n0 + wn + j * 16 + lr;
        const float bv = biasAll[gc];
#pragma unroll
        for (int r = 0; r < 4; ++r) {
          const int gr = m0 + wm + i * 16 + (l >> 4) * 4 + r;
          const float v = acc[i][j][r] + bv;
          const unsigned short bfv = f2bf(v);
          if (gc < CDIM) {
            qb[(size_t)gr * CDIM + gc] = bfv;
          } else {
            const int cc = (gc < 2 * CDIM) ? gc - CDIM : gc - 2 * CDIM;
            const int zy = gr / DD, xx = gr - zy * DD;
            const int dst = zy * LSTRIDE + (cc >> 3) * (DD * 8) + xx * 8 + (cc & 7);
            if (gc < 2 * CDIM) kxb[dst] = bfv;
            else               vxb[dst] = bfv;
          }
        }
      }
  }
}

// x-line attention on x-interleaved k/v. One wave per (z,y,head); lane =
// (x in 0..27, g half-head); lane owns 24 ch (3 16B units). Slice load
// [cg][x+d][8ch]: consecutive lanes 16B apart -> ~8 cache lines per wave
// load (coalesced), vs 28-56 for vox-major. K phase then V phase per row.
// OOB slots (reference zero-pads k/v AFTER bias): logit 0 counted in the
// softmax denominator -> closed-form init m=0, s=noob.
__global__ __launch_bounds__(256, 3) void attn3d_xint(
    const unsigned short* __restrict__ q,   // [vox][192]
    const unsigned short* __restrict__ kx,  // [784][24][28][8]
    const unsigned short* __restrict__ vx,  // [784][24][28][8]
    unsigned short* __restrict__ y)         // [vox][192]
{
  const int bid = blockIdx.x;
  const int zy = (bid & 7) * 98 + (bid >> 3);   // 784 = 8*98 bijective
  const int z = zy / 28, yr = zy % 28;
  const int h = threadIdx.x >> 6;
  const int lane = threadIdx.x & 63;
  const int x = lane & 31;
  const int xc = x < 28 ? x : 27;               // clamp idle lanes
  const int g = lane >> 5;
  const int cb = h * 48 + g * 24;
  const int cgb = h * 6 + g * 3;                // 16B-unit base
  const int vox = zy * 28 + xc;

  float qf[24];
  {
    const uint4* qp = (const uint4*)(q + (size_t)vox * CDIM + cb);
    const uint4 a = qp[0], b = qp[1], c = qp[2];
    const unsigned int uu[12] = {a.x, a.y, a.z, a.w, b.x, b.y, b.z, b.w,
                                 c.x, c.y, c.z, c.w};
#pragma unroll
    for (int i = 0; i < 12; ++i) { qf[2*i] = blo(uu[i]); qf[2*i+1] = bhi(uu[i]); }
  }

  const int nx = 3 - (x == 0) - (x == 27);
  const int ny = 3 - (yr == 0) - (yr == 27);
  const int nz = 3 - (z == 0) - (z == 27);
  const int noob = 27 - nx * ny * nz;
  float m = noob ? 0.f : -INFINITY;
  float s = (float)noob;
  float out[24];
#pragma unroll
  for (int i = 0; i < 24; ++i) out[i] = 0.f;

  const bool okm = (x > 0), okp = (x < 27);
  const int xm = okm ? xc - 1 : 0;
  const int xp = okp ? xc + 1 : 27;

  // ushort offsets within a line for (unit i, slice) combos
  int offm[3], offc[3], offp[3];
#pragma unroll
  for (int i = 0; i < 3; ++i) {
    const int ub = (cgb + i) * (DD * 8);
    offm[i] = ub + xm * 8; offc[i] = ub + xc * 8; offp[i] = ub + xp * 8;
  }

  for (int dz = -1; dz <= 1; ++dz) {
    const int zz = z + dz;
    if ((unsigned)zz >= 28u) continue;          // block-uniform
    for (int dy = -1; dy <= 1; ++dy) {
      const int yv = yr + dy;
      if ((unsigned)yv >= 28u) continue;        // block-uniform
      const size_t lbase = (size_t)(zz * 28 + yv) * LSTRIDE;
      const unsigned short* kl = kx + lbase;
      const unsigned short* vl = vx + lbase;

      // ---- K phase ----
      const uint4 Km0 = *(const uint4*)(kl + offm[0]);
      const uint4 Km1 = *(const uint4*)(kl + offm[1]);
      const uint4 Km2 = *(const uint4*)(kl + offm[2]);
      const uint4 Kc0 = *(const uint4*)(kl + offc[0]);
      const uint4 Kc1 = *(const uint4*)(kl + offc[1]);
      const uint4 Kc2 = *(const uint4*)(kl + offc[2]);
      const uint4 Kp0 = *(const uint4*)(kl + offp[0]);
      const uint4 Kp1 = *(const uint4*)(kl + offp[1]);
      const uint4 Kp2 = *(const uint4*)(kl + offp[2]);
      const unsigned int km[12] = {Km0.x, Km0.y, Km0.z, Km0.w, Km1.x, Km1.y,
                                   Km1.z, Km1.w, Km2.x, Km2.y, Km2.z, Km2.w};
      const unsigned int kc[12] = {Kc0.x, Kc0.y, Kc0.z, Kc0.w, Kc1.x, Kc1.y,
                                   Kc1.z, Kc1.w, Kc2.x, Kc2.y, Kc2.z, Kc2.w};
      const unsigned int kp[12] = {Kp0.x, Kp0.y, Kp0.z, Kp0.w, Kp1.x, Kp1.y,
                                   Kp1.z, Kp1.w, Kp2.x, Kp2.y, Kp2.z, Kp2.w};
      float p0 = 0.f, p1 = 0.f, p2 = 0.f;
#pragma unroll
      for (int i = 0; i < 12; ++i) {
        p0 += qf[2*i] * blo(km[i]) + qf[2*i+1] * bhi(km[i]);
        p1 += qf[2*i] * blo(kc[i]) + qf[2*i+1] * bhi(kc[i]);
        p2 += qf[2*i] * blo(kp[i]) + qf[2*i+1] * bhi(kp[i]);
      }
      p0 += __shfl_xor(p0, 32);   // combine half-head partials
      p1 += __shfl_xor(p1, 32);
      p2 += __shfl_xor(p2, 32);

      // ---- issue V loads before softmax (latency overlap) ----
      const uint4 Vm0 = *(const uint4*)(vl + offm[0]);
      const uint4 Vm1 = *(const uint4*)(vl + offm[1]);
      const uint4 Vm2 = *(const uint4*)(vl + offm[2]);
      const uint4 Vc0 = *(const uint4*)(vl + offc[0]);
      const uint4 Vc1 = *(const uint4*)(vl + offc[1]);
      const uint4 Vc2 = *(const uint4*)(vl + offc[2]);
      const uint4 Vp0 = *(const uint4*)(vl + offp[0]);
      const uint4 Vp1 = *(const uint4*)(vl + offp[1]);
      const uint4 Vp2 = *(const uint4*)(vl + offp[2]);

      const float l0 = okm ? p0 : -INFINITY;
      const float l2 = okp ? p2 : -INFINITY;
      const float nm = fmaxf(m, fmaxf(p1, fmaxf(l0, l2)));
      const float sc = __expf(m - nm);
      const float w0 = okm ? __expf(p0 - nm) : 0.f;
      const float w1 = __expf(p1 - nm);
      const float w2 = okp ? __expf(p2 - nm) : 0.f;
      s = s * sc + w0 + w1 + w2;
      m = nm;

      const unsigned int vm[12] = {Vm0.x, Vm0.y, Vm0.z, Vm0.w, Vm1.x, Vm1.y,
                                   Vm1.z, Vm1.w, Vm2.x, Vm2.y, Vm2.z, Vm2.w};
      const unsigned int vc[12] = {Vc0.x, Vc0.y, Vc0.z, Vc0.w, Vc1.x, Vc1.y,
                                   Vc1.z, Vc1.w, Vc2.x, Vc2.y, Vc2.z, Vc2.w};
      const unsigned int vp[12] = {Vp0.x, Vp0.y, Vp0.z, Vp0.w, Vp1.x, Vp1.y,
                                   Vp1.z, Vp1.w, Vp2.x, Vp2.y, Vp2.z, Vp2.w};
#pragma unroll
      for (int i = 0; i < 12; ++i) {
        out[2*i]   = out[2*i]   * sc + w0 * blo(vm[i]) + w1 * blo(vc[i]) + w2 * blo(vp[i]);
        out[2*i+1] = out[2*i+1] * sc + w0 * bhi(vm[i]) + w1 * bhi(vc[i]) + w2 * bhi(vp[i]);
      }
    }
  }

  if (x < 28) {
    const float inv = 1.f / s;
    unsigned int ou[12];
#pragma unroll
    for (int i = 0; i < 12; ++i)
      ou[i] = pk2(out[2*i] * inv, out[2*i+1] * inv);
    uint4* yp = (uint4*)(y + (size_t)vox * CDIM + cb);
    yp[0] = make_uint4(ou[0], ou[1], ou[2], ou[3]);
    yp[1] = make_uint4(ou[4], ou[5], ou[6], ou[7]);
    yp[2] = make_uint4(ou[8], ou[9], ou[10], ou[11]);
  }
}

// Output projection: out = y @ WpT^T + bp, fp32 out. 64x64 tiles, grid (3,343).
__global__ __launch_bounds__(256) void gemm_out(
    const unsigned short* __restrict__ A,
    const unsigned short* __restrict__ Bt,
    const float* __restrict__ bias,
    float* __restrict__ C)
{
  __shared__ unsigned short As[64 * 200];
  __shared__ unsigned short Bs[64 * 200];
  const int tid = threadIdx.x;
  const int n0 = blockIdx.x * 64;
  const int m0 = blockIdx.y * 64;

#pragma unroll
  for (int u = tid; u < 1536; u += 256) {
    const int row = u / 24, c = (u % 24) * 8;
    *(uint4*)(&As[row * 200 + c]) =
        *(const uint4*)(&A[(size_t)(m0 + row) * CDIM + c]);
    *(uint4*)(&Bs[row * 200 + c]) =
        *(const uint4*)(&Bt[(size_t)(n0 + row) * CDIM + c]);
  }
  __syncthreads();

  const int l = tid & 63, w = tid >> 6;
  const int wm = (w >> 1) * 32, wn = (w & 1) * 32;
  const int lr = l & 15, lk = (l >> 4) * 8;

  f32x4 acc[2][2] = {};
  const unsigned short* pa = &As[(wm + lr) * 200 + lk];
  const unsigned short* pb = &Bs[(wn + lr) * 200 + lk];

#pragma unroll
  for (int k0 = 0; k0 < CDIM; k0 += 32) {
    const bf16x8 a0 = *(const bf16x8*)(pa + k0);
    const bf16x8 a1 = *(const bf16x8*)(pa + 16 * 200 + k0);
    const bf16x8 b0 = *(const bf16x8*)(pb + k0);
    const bf16x8 b1 = *(const bf16x8*)(pb + 16 * 200 + k0);
    acc[0][0] = __builtin_amdgcn_mfma_f32_16x16x32_bf16(a0, b0, acc[0][0], 0, 0, 0);
    acc[0][1] = __builtin_amdgcn_mfma_f32_16x16x32_bf16(a0, b1, acc[0][1], 0, 0, 0);
    acc[1][0] = __builtin_amdgcn_mfma_f32_16x16x32_bf16(a1, b0, acc[1][0], 0, 0, 0);
    acc[1][1] = __builtin_amdgcn_mfma_f32_16x16x32_bf16(a1, b1, acc[1][1], 0, 0, 0);
  }

#pragma unroll
  for (int i = 0; i < 2; ++i)
#pragma unroll
    for (int j = 0; j < 2; ++j) {
      const int gc = n0 + wn + j * 16 + lr;
      const float bv = bias[gc];
#pragma unroll
      for (int r = 0; r < 4; ++r) {
        const int gr = m0 + wm + i * 16 + (l >> 4) * 4 + r;
        C[(size_t)gr * CDIM + gc] = acc[i][j][r] + bv;
      }
    }
}

extern "C" void kernel_launch(void* const* d_in, const int* in_sizes, int n_in,
                              void* d_out, int out_size, void* d_ws, size_t ws_size,
                              hipStream_t stream) {
  const float* x   = (const float*)d_in[0];
  const float* Wq  = (const float*)d_in[1];
  const float* bq  = (const float*)d_in[2];
  const float* Wkv = (const float*)d_in[3];
  const float* bkv = (const float*)d_in[4];
  const float* Wp  = (const float*)d_in[5];
  const float* bp  = (const float*)d_in[6];
  float* out = (float*)d_out;

  unsigned short* WqkvT = (unsigned short*)d_ws;          // 576*192
  unsigned short* WpT   = WqkvT + 576 * CDIM;             // 192*192
  float*          biasA = (float*)(WpT + CDIM * CDIM);    // 576 floats
  unsigned short* qb    = (unsigned short*)(biasA + 576); // NVOX*192
  unsigned short* kxb   = qb + (size_t)NVOX * CDIM;       // 784*5376
  unsigned short* vxb   = kxb + (size_t)NLINE * LSTRIDE;  // 784*5376
  unsigned short* yb    = vxb + (size_t)NLINE * LSTRIDE;  // NVOX*192

  const float scale = 1.0f / sqrtf(48.0f);

  prep_w<<<(148032 + 255) / 256, 256, 0, stream>>>(
      Wq, Wkv, Wp, bq, bkv, WqkvT, WpT, biasA, scale);

  gemm_qkv<<<dim3(NVOX / 64, 3), 256, 0, stream>>>(x, WqkvT, biasA, qb, kxb, vxb);
  attn3d_xint<<<NLINE, 256, 0, stream>>>(qb, kxb, vxb, yb);
  gemm_out<<<dim3(3, NVOX / 64), 256, 0, stream>>>(yb, WpT, bp, out);
}

// Round 11
// 144.605 us; speedup vs baseline: 1.3175x; 1.0151x over previous
//
#include <hip/hip_runtime.h>
#include <hip/hip_bf16.h>
#include <math.h>

#define CDIM 192
#define DD 28
#define NVOX (DD * DD * DD)   // 21952
#define NLINE (DD * DD)       // 784
#define LSTRIDE (24 * DD * 8) // 5376 ushorts per line (24 cg x 28 x x 8ch)

typedef __attribute__((ext_vector_type(8))) short bf16x8;
typedef __attribute__((ext_vector_type(4))) float f32x4;

__device__ __forceinline__ float blo(unsigned int u) {
  union { unsigned int i; float f; } w; w.i = u << 16; return w.f;
}
__device__ __forceinline__ float bhi(unsigned int u) {
  union { unsigned int i; float f; } w; w.i = u & 0xffff0000u; return w.f;
}
__device__ __forceinline__ unsigned short f2bf(float f) {
  union { float ff; unsigned int i; } w; w.ff = f;
  unsigned int x = w.i;
  return (unsigned short)((x + 0x7fffu + ((x >> 16) & 1u)) >> 16);  // RNE
}
__device__ __forceinline__ unsigned int pk2(float lo, float hi) {
  __hip_bfloat162 h = __float22bfloat162_rn(make_float2(lo, hi));
  union { __hip_bfloat162 h2; unsigned int u; } cv; cv.h2 = h; return cv.u;
}

// prep: weights -> bf16, transposed to [n][k]; scale folded into Wq/bq.
__global__ __launch_bounds__(256) void prep_w(
    const float* __restrict__ Wq, const float* __restrict__ Wkv,
    const float* __restrict__ Wp, const float* __restrict__ bq,
    const float* __restrict__ bkv,
    unsigned short* __restrict__ WqkvT, unsigned short* __restrict__ WpT,
    float* __restrict__ biasAll, float scale)
{
  int t = blockIdx.x * 256 + threadIdx.x;
  if (t < 576 * CDIM) {
    const int n = t / CDIM, k = t % CDIM;
    const float v = (n < CDIM) ? Wq[k * CDIM + n] * scale
                               : Wkv[k * 2 * CDIM + (n - CDIM)];
    WqkvT[t] = f2bf(v);
    return;
  }
  t -= 576 * CDIM;
  if (t < CDIM * CDIM) {
    const int n = t / CDIM, k = t % CDIM;
    WpT[t] = f2bf(Wp[k * CDIM + n]);
    return;
  }
  t -= CDIM * CDIM;
  if (t < 576)
    biasAll[t] = (t < CDIM) ? bq[t] * scale : bkv[t - CDIM];
}

// Fused QKV GEMM. q -> vox-major [vox][192]; k,v -> x-interleaved
// [line][cg][x][8ch] so attention slice-loads are lane-coalesced.
__global__ __launch_bounds__(256) void gemm_qkv(
    const float* __restrict__ X,            // [M][192] fp32
    const unsigned short* __restrict__ Bt,  // [576][192] bf16
    const float* __restrict__ biasAll,      // [576]
    unsigned short* __restrict__ qb,        // [vox][192]
    unsigned short* __restrict__ kxb,       // [784][24][28][8]
    unsigned short* __restrict__ vxb)       // [784][24][28][8]
{
  __shared__ unsigned short As[64 * 200];
  __shared__ unsigned short Bs[64 * 200];
  const int tid = threadIdx.x;
  const int m0 = blockIdx.x * 64;
  const int by = blockIdx.y;

#pragma unroll
  for (int u = tid; u < 1536; u += 256) {  // 64 rows x 24 8-elem units
    const int row = u / 24, c = (u % 24) * 8;
    const float4 f0 = *(const float4*)(&X[(size_t)(m0 + row) * CDIM + c]);
    const float4 f1 = *(const float4*)(&X[(size_t)(m0 + row) * CDIM + c + 4]);
    unsigned int o[4] = {pk2(f0.x, f0.y), pk2(f0.z, f0.w),
                         pk2(f1.x, f1.y), pk2(f1.z, f1.w)};
    *(uint4*)(&As[row * 200 + c]) = *(const uint4*)o;
  }

  const int l = tid & 63, w = tid >> 6;
  const int wm = (w >> 1) * 32, wn = (w & 1) * 32;
  const int lr = l & 15, lk = (l >> 4) * 8;
  const unsigned short* pa = &As[(wm + lr) * 200 + lk];
  const unsigned short* pb = &Bs[(wn + lr) * 200 + lk];

  for (int nt = by; nt < 9; nt += 3) {
    const int n0 = nt * 64;
    __syncthreads();  // iter 0: As ready; later: prev Bs readers done
#pragma unroll
    for (int u = tid; u < 1536; u += 256) {
      const int row = u / 24, c = (u % 24) * 8;
      *(uint4*)(&Bs[row * 200 + c]) =
          *(const uint4*)(&Bt[(size_t)(n0 + row) * CDIM + c]);
    }
    __syncthreads();

    f32x4 acc[2][2] = {};
#pragma unroll
    for (int k0 = 0; k0 < CDIM; k0 += 32) {
      const bf16x8 a0 = *(const bf16x8*)(pa + k0);
      const bf16x8 a1 = *(const bf16x8*)(pa + 16 * 200 + k0);
      const bf16x8 b0 = *(const bf16x8*)(pb + k0);
      const bf16x8 b1 = *(const bf16x8*)(pb + 16 * 200 + k0);
      acc[0][0] = __builtin_amdgcn_mfma_f32_16x16x32_bf16(a0, b0, acc[0][0], 0, 0, 0);
      acc[0][1] = __builtin_amdgcn_mfma_f32_16x16x32_bf16(a0, b1, acc[0][1], 0, 0, 0);
      acc[1][0] = __builtin_amdgcn_mfma_f32_16x16x32_bf16(a1, b0, acc[1][0], 0, 0, 0);
      acc[1][1] = __builtin_amdgcn_mfma_f32_16x16x32_bf16(a1, b1, acc[1][1], 0, 0, 0);
    }

    // C/D: col = lane&15, row = (lane>>4)*4 + reg
#pragma unroll
    for (int i = 0; i < 2; ++i)
#pragma unroll
      for (int j = 0; j < 2; ++j) {
        const int gc = n0 + wn + j * 16 + lr;
        const float bv = biasAll[gc];
#pragma unroll
        for (int r = 0; r < 4; ++r) {
          const int gr = m0 + wm + i * 16 + (l >> 4) * 4 + r;
          const float v = acc[i][j][r] + bv;
          const unsigned short bfv = f2bf(v);
          if (gc < CDIM) {
            qb[(size_t)gr * CDIM + gc] = bfv;
          } else {
            const int cc = (gc < 2 * CDIM) ? gc - CDIM : gc - 2 * CDIM;
            const int zy = gr / DD, xx = gr - zy * DD;
            const int dst = zy * LSTRIDE + (cc >> 3) * (DD * 8) + xx * 8 + (cc & 7);
            if (gc < 2 * CDIM) kxb[dst] = bfv;
            else               vxb[dst] = bfv;
          }
        }
      }
  }
}

// Fused x-line attention + output projection. One wave per (z,y,head);
// lane = (x, half-head g); lane owns 24 ch. Coalesced x-interleaved k/v
// slice loads. After online softmax, the block's full 28x192 y-tile goes
// to LDS (bf16, stride 200, rows 28..31 zeroed) and the 4 waves run a
// 32x192x192 MFMA against WpT (global, L1/L2-hot) writing fp32 out.
// OOB slots (reference zero-pads k/v AFTER bias): logit 0 counted in the
// softmax denominator -> closed-form init m=0, s=noob.
__global__ __launch_bounds__(256, 3) void attn3d_proj(
    const unsigned short* __restrict__ q,    // [vox][192]
    const unsigned short* __restrict__ kx,   // [784][24][28][8]
    const unsigned short* __restrict__ vx,   // [784][24][28][8]
    const unsigned short* __restrict__ WpT,  // [192][192] bf16 [n][k]
    const float* __restrict__ bp,            // [192]
    float* __restrict__ C)                   // [vox][192] fp32
{
  __shared__ unsigned short ytile[32 * 200];

  const int bid = blockIdx.x;
  const int zy = (bid & 7) * 98 + (bid >> 3);   // 784 = 8*98 bijective
  const int z = zy / 28, yr = zy % 28;
  const int h = threadIdx.x >> 6;
  const int lane = threadIdx.x & 63;
  const int x = lane & 31;
  const int xc = x < 28 ? x : 27;               // clamp idle lanes
  const int g = lane >> 5;
  const int cb = h * 48 + g * 24;
  const int cgb = h * 6 + g * 3;                // 16B-unit base
  const int vox = zy * 28 + xc;

  // zero the M-pad rows (28..31) of the y-tile: 4*200 ushorts = 100 uint4
  if (threadIdx.x < 100)
    *(uint4*)(&ytile[28 * 200 + threadIdx.x * 8]) = make_uint4(0, 0, 0, 0);

  float qf[24];
  {
    const uint4* qp = (const uint4*)(q + (size_t)vox * CDIM + cb);
    const uint4 a = qp[0], b = qp[1], c = qp[2];
    const unsigned int uu[12] = {a.x, a.y, a.z, a.w, b.x, b.y, b.z, b.w,
                                 c.x, c.y, c.z, c.w};
#pragma unroll
    for (int i = 0; i < 12; ++i) { qf[2*i] = blo(uu[i]); qf[2*i+1] = bhi(uu[i]); }
  }

  const int nx = 3 - (x == 0) - (x == 27);
  const int ny = 3 - (yr == 0) - (yr == 27);
  const int nz = 3 - (z == 0) - (z == 27);
  const int noob = 27 - nx * ny * nz;
  float m = noob ? 0.f : -INFINITY;
  float s = (float)noob;
  float out[24];
#pragma unroll
  for (int i = 0; i < 24; ++i) out[i] = 0.f;

  const bool okm = (x > 0), okp = (x < 27);
  const int xm = okm ? xc - 1 : 0;
  const int xp = okp ? xc + 1 : 27;

  int offm[3], offc[3], offp[3];
#pragma unroll
  for (int i = 0; i < 3; ++i) {
    const int ub = (cgb + i) * (DD * 8);
    offm[i] = ub + xm * 8; offc[i] = ub + xc * 8; offp[i] = ub + xp * 8;
  }

  for (int dz = -1; dz <= 1; ++dz) {
    const int zz = z + dz;
    if ((unsigned)zz >= 28u) continue;          // block-uniform
    for (int dy = -1; dy <= 1; ++dy) {
      const int yv = yr + dy;
      if ((unsigned)yv >= 28u) continue;        // block-uniform
      const size_t lbase = (size_t)(zz * 28 + yv) * LSTRIDE;
      const unsigned short* kl = kx + lbase;
      const unsigned short* vl = vx + lbase;

      // ---- K phase ----
      const uint4 Km0 = *(const uint4*)(kl + offm[0]);
      const uint4 Km1 = *(const uint4*)(kl + offm[1]);
      const uint4 Km2 = *(const uint4*)(kl + offm[2]);
      const uint4 Kc0 = *(const uint4*)(kl + offc[0]);
      const uint4 Kc1 = *(const uint4*)(kl + offc[1]);
      const uint4 Kc2 = *(const uint4*)(kl + offc[2]);
      const uint4 Kp0 = *(const uint4*)(kl + offp[0]);
      const uint4 Kp1 = *(const uint4*)(kl + offp[1]);
      const uint4 Kp2 = *(const uint4*)(kl + offp[2]);
      const unsigned int km[12] = {Km0.x, Km0.y, Km0.z, Km0.w, Km1.x, Km1.y,
                                   Km1.z, Km1.w, Km2.x, Km2.y, Km2.z, Km2.w};
      const unsigned int kc[12] = {Kc0.x, Kc0.y, Kc0.z, Kc0.w, Kc1.x, Kc1.y,
                                   Kc1.z, Kc1.w, Kc2.x, Kc2.y, Kc2.z, Kc2.w};
      const unsigned int kp[12] = {Kp0.x, Kp0.y, Kp0.z, Kp0.w, Kp1.x, Kp1.y,
                                   Kp1.z, Kp1.w, Kp2.x, Kp2.y, Kp2.z, Kp2.w};
      float p0 = 0.f, p1 = 0.f, p2 = 0.f;
#pragma unroll
      for (int i = 0; i < 12; ++i) {
        p0 += qf[2*i] * blo(km[i]) + qf[2*i+1] * bhi(km[i]);
        p1 += qf[2*i] * blo(kc[i]) + qf[2*i+1] * bhi(kc[i]);
        p2 += qf[2*i] * blo(kp[i]) + qf[2*i+1] * bhi(kp[i]);
      }
      p0 += __shfl_xor(p0, 32);   // combine half-head partials
      p1 += __shfl_xor(p1, 32);
      p2 += __shfl_xor(p2, 32);

      // ---- issue V loads before softmax (latency overlap) ----
      const uint4 Vm0 = *(const uint4*)(vl + offm[0]);
      const uint4 Vm1 = *(const uint4*)(vl + offm[1]);
      const uint4 Vm2 = *(const uint4*)(vl + offm[2]);
      const uint4 Vc0 = *(const uint4*)(vl + offc[0]);
      const uint4 Vc1 = *(const uint4*)(vl + offc[1]);
      const uint4 Vc2 = *(const uint4*)(vl + offc[2]);
      const uint4 Vp0 = *(const uint4*)(vl + offp[0]);
      const uint4 Vp1 = *(const uint4*)(vl + offp[1]);
      const uint4 Vp2 = *(const uint4*)(vl + offp[2]);

      const float l0 = okm ? p0 : -INFINITY;
      const float l2 = okp ? p2 : -INFINITY;
      const float nm = fmaxf(m, fmaxf(p1, fmaxf(l0, l2)));
      const float sc = __expf(m - nm);
      const float w0 = okm ? __expf(p0 - nm) : 0.f;
      const float w1 = __expf(p1 - nm);
      const float w2 = okp ? __expf(p2 - nm) : 0.f;
      s = s * sc + w0 + w1 + w2;
      m = nm;

      const unsigned int vm[12] = {Vm0.x, Vm0.y, Vm0.z, Vm0.w, Vm1.x, Vm1.y,
                                   Vm1.z, Vm1.w, Vm2.x, Vm2.y, Vm2.z, Vm2.w};
      const unsigned int vc[12] = {Vc0.x, Vc0.y, Vc0.z, Vc0.w, Vc1.x, Vc1.y,
                                   Vc1.z, Vc1.w, Vc2.x, Vc2.y, Vc2.z, Vc2.w};
      const unsigned int vp[12] = {Vp0.x, Vp0.y, Vp0.z, Vp0.w, Vp1.x, Vp1.y,
                                   Vp1.z, Vp1.w, Vp2.x, Vp2.y, Vp2.z, Vp2.w};
#pragma unroll
      for (int i = 0; i < 12; ++i) {
        out[2*i]   = out[2*i]   * sc + w0 * blo(vm[i]) + w1 * blo(vc[i]) + w2 * blo(vp[i]);
        out[2*i+1] = out[2*i+1] * sc + w0 * bhi(vm[i]) + w1 * bhi(vc[i]) + w2 * bhi(vp[i]);
      }
    }
  }

  // ---- y-tile to LDS (bf16) ----
  if (x < 28) {
    const float inv = 1.f / s;
    unsigned int ou[12];
#pragma unroll
    for (int i = 0; i < 12; ++i)
      ou[i] = pk2(out[2*i] * inv, out[2*i+1] * inv);
    uint4* yp = (uint4*)(&ytile[xc * 200 + cb]);
    yp[0] = make_uint4(ou[0], ou[1], ou[2], ou[3]);
    yp[1] = make_uint4(ou[4], ou[5], ou[6], ou[7]);
    yp[2] = make_uint4(ou[8], ou[9], ou[10], ou[11]);
  }
  __syncthreads();

  // ---- projection: C[28x192] = y[28x192] @ WpT^T + bp ----
  const int w = threadIdx.x >> 6;
  const int lr = lane & 15, lk = (lane >> 4) * 8;
  const int nb = w * 48;                       // wave's 48-col slab

  f32x4 acc[2][3] = {};
#pragma unroll
  for (int k0 = 0; k0 < CDIM; k0 += 32) {
    const bf16x8 a0 = *(const bf16x8*)(&ytile[(0 + lr) * 200 + lk + k0]);
    const bf16x8 a1 = *(const bf16x8*)(&ytile[(16 + lr) * 200 + lk + k0]);
#pragma unroll
    for (int nj = 0; nj < 3; ++nj) {
      const bf16x8 b = *(const bf16x8*)(
          &WpT[(size_t)(nb + nj * 16 + lr) * CDIM + lk + k0]);
      acc[0][nj] = __builtin_amdgcn_mfma_f32_16x16x32_bf16(a0, b, acc[0][nj], 0, 0, 0);
      acc[1][nj] = __builtin_amdgcn_mfma_f32_16x16x32_bf16(a1, b, acc[1][nj], 0, 0, 0);
    }
  }

  // C/D: col = lane&15, row = (lane>>4)*4 + reg
#pragma unroll
  for (int nj = 0; nj < 3; ++nj) {
    const int gc = nb + nj * 16 + lr;
    const float bv = bp[gc];
#pragma unroll
    for (int mi = 0; mi < 2; ++mi)
#pragma unroll
      for (int r = 0; r < 4; ++r) {
        const int row = mi * 16 + (lane >> 4) * 4 + r;
        if (row < 28)
          C[(size_t)(zy * 28 + row) * CDIM + gc] = acc[mi][nj][r] + bv;
      }
  }
}

extern "C" void kernel_launch(void* const* d_in, const int* in_sizes, int n_in,
                              void* d_out, int out_size, void* d_ws, size_t ws_size,
                              hipStream_t stream) {
  const float* x   = (const float*)d_in[0];
  const float* Wq  = (const float*)d_in[1];
  const float* bq  = (const float*)d_in[2];
  const float* Wkv = (const float*)d_in[3];
  const float* bkv = (const float*)d_in[4];
  const float* Wp  = (const float*)d_in[5];
  const float* bp  = (const float*)d_in[6];
  float* out = (float*)d_out;

  unsigned short* WqkvT = (unsigned short*)d_ws;          // 576*192
  unsigned short* WpT   = WqkvT + 576 * CDIM;             // 192*192
  float*          biasA = (float*)(WpT + CDIM * CDIM);    // 576 floats
  unsigned short* qb    = (unsigned short*)(biasA + 576); // NVOX*192
  unsigned short* kxb   = qb + (size_t)NVOX * CDIM;       // 784*5376
  unsigned short* vxb   = kxb + (size_t)NLINE * LSTRIDE;  // 784*5376

  const float scale = 1.0f / sqrtf(48.0f);

  prep_w<<<(148032 + 255) / 256, 256, 0, stream>>>(
      Wq, Wkv, Wp, bq, bkv, WqkvT, WpT, biasA, scale);

  gemm_qkv<<<dim3(NVOX / 64, 3), 256, 0, stream>>>(x, WqkvT, biasA, qb, kxb, vxb);
  attn3d_proj<<<NLINE, 256, 0, stream>>>(qb, kxb, vxb, WpT, bp, out);
}

// Round 13
// 136.542 us; speedup vs baseline: 1.3953x; 1.0590x over previous
//
#include <hip/hip_runtime.h>
#include <hip/hip_bf16.h>
#include <math.h>

#define CDIM 192
#define DD 28
#define NVOX (DD * DD * DD)   // 21952
#define NLINE (DD * DD)       // 784
#define LSTRIDE (24 * DD * 8) // 5376 ushorts per kv line
#define LSTR 208              // LDS row stride (ushorts)
#define SCALE 0.14433756729740643f  // 48^-0.5

typedef __attribute__((ext_vector_type(8))) short bf16x8;
typedef __attribute__((ext_vector_type(4))) float f32x4;

__device__ __forceinline__ float blo(unsigned int u) {
  union { unsigned int i; float f; } w; w.i = u << 16; return w.f;
}
__device__ __forceinline__ float bhi(unsigned int u) {
  union { unsigned int i; float f; } w; w.i = u & 0xffff0000u; return w.f;
}
__device__ __forceinline__ unsigned short f2bf(float f) {
  union { float ff; unsigned int i; } w; w.ff = f;
  unsigned int x = w.i;
  return (unsigned short)((x + 0x7fffu + ((x >> 16) & 1u)) >> 16);  // RNE
}
__device__ __forceinline__ unsigned int pk2(float lo, float hi) {
  __hip_bfloat162 h = __float22bfloat162_rn(make_float2(lo, hi));
  union { __hip_bfloat162 h2; unsigned int u; } cv; cv.h2 = h; return cv.u;
}

// Pack weights into MFMA B-fragment order:
// wpack[ng][ks][lane][e]: n = ng*16+(lane&15), k = ks*32+(lane>>4)*8+e.
// A wave's B-frag load is then ONE coalesced 1KB read.
__global__ __launch_bounds__(256) void prep_pack(
    const float* __restrict__ Wq, const float* __restrict__ bq,
    const float* __restrict__ Wkv, const float* __restrict__ bkv,
    const float* __restrict__ Wp,
    unsigned short* __restrict__ wpack,  // [36][6][64][8]
    unsigned short* __restrict__ ppack,  // [12][6][64][8]
    float* __restrict__ biasA)           // [576]
{
  int t = blockIdx.x * 256 + threadIdx.x;
  if (t < 110592) {
    const int e = t & 7, ln = (t >> 3) & 63;
    const int ks = (t >> 9) % 6, ng = (t >> 9) / 6;
    const int n = ng * 16 + (ln & 15);
    const int k = ks * 32 + (ln >> 4) * 8 + e;
    const float v = (n < CDIM) ? Wq[k * CDIM + n] * SCALE
                               : Wkv[k * 2 * CDIM + (n - CDIM)];
    wpack[t] = f2bf(v);
  } else if (t < 147456) {
    const int u = t - 110592;
    const int e = u & 7, ln = (u >> 3) & 63;
    const int ks = (u >> 9) % 6, ng = (u >> 9) / 6;
    const int n = ng * 16 + (ln & 15);
    const int k = ks * 32 + (ln >> 4) * 8 + e;
    ppack[u] = f2bf(Wp[k * CDIM + n]);
  } else if (t < 148032) {
    const int u = t - 147456;
    biasA[u] = (u < CDIM) ? bq[u] * SCALE : bkv[u - CDIM];
  }
}

// Per-line QKV GEMM: block = line (z,y). x-line staged ONCE to LDS (bf16),
// B-frags streamed coalesced from wpack (L2-hot, 221 KB). One barrier total.
// q -> vox-major; k/v -> x-interleaved [line][cg][x][8ch].
__global__ __launch_bounds__(256, 4) void qkv_line(
    const float* __restrict__ X,            // [NVOX][192] fp32
    const unsigned short* __restrict__ wpack,
    const float* __restrict__ biasA,
    unsigned short* __restrict__ qb,        // [vox][192]
    unsigned short* __restrict__ kxb,       // [784][24][28][8]
    unsigned short* __restrict__ vxb)       // [784][24][28][8]
{
  __shared__ __align__(16) unsigned short As[32 * LSTR];
  const int tid = threadIdx.x;
  const int zy = blockIdx.x;

  for (int u = tid; u < 672; u += 256) {   // 28 rows x 24 8-float units
    const int row = u / 24, c = (u % 24) * 8;
    const float4 f0 = *(const float4*)(&X[(size_t)(zy * 28 + row) * CDIM + c]);
    const float4 f1 = *(const float4*)(&X[(size_t)(zy * 28 + row) * CDIM + c + 4]);
    unsigned int o[4] = {pk2(f0.x, f0.y), pk2(f0.z, f0.w),
                         pk2(f1.x, f1.y), pk2(f1.z, f1.w)};
    *(uint4*)(&As[row * LSTR + c]) = *(const uint4*)o;
  }
  for (int u = tid; u < 104; u += 256) {   // zero pad rows 28..31
    const int row = 28 + u / 26, c = (u % 26) * 8;
    *(uint4*)(&As[row * LSTR + c]) = make_uint4(0, 0, 0, 0);
  }
  __syncthreads();

  const int w = tid >> 6;
  const int lane = tid & 63;
  const int lr = lane & 15, lk = (lane >> 4) * 8;

  f32x4 acc[2][9] = {};
#pragma unroll
  for (int ks = 0; ks < 6; ++ks) {
    const bf16x8 a0 = *(const bf16x8*)(&As[lr * LSTR + ks * 32 + lk]);
    const bf16x8 a1 = *(const bf16x8*)(&As[(16 + lr) * LSTR + ks * 32 + lk]);
#pragma unroll
    for (int j = 0; j < 9; ++j) {
      const int ng = w * 9 + j;
      const bf16x8 b = *(const bf16x8*)(&wpack[((ng * 6 + ks) * 64 + lane) * 8]);
      acc[0][j] = __builtin_amdgcn_mfma_f32_16x16x32_bf16(a0, b, acc[0][j], 0, 0, 0);
      acc[1][j] = __builtin_amdgcn_mfma_f32_16x16x32_bf16(a1, b, acc[1][j], 0, 0, 0);
    }
  }

  // C/D: col = lane&15 (-> channel n), row = (lane>>4)*4 + r (-> x)
#pragma unroll
  for (int j = 0; j < 9; ++j) {
    const int n = (w * 9 + j) * 16 + lr;
    const float bv = biasA[n];
#pragma unroll
    for (int mi = 0; mi < 2; ++mi)
#pragma unroll
      for (int rr = 0; rr < 4; ++rr) {
        const int row = mi * 16 + (lane >> 4) * 4 + rr;
        if (row < 28) {
          const unsigned short bfv = f2bf(acc[mi][j][rr] + bv);
          if (n < CDIM) {
            qb[(size_t)(zy * 28 + row) * CDIM + n] = bfv;
          } else {
            const int c = n - CDIM;
            const int cc = (c < CDIM) ? c : c - CDIM;
            const int dst = zy * LSTRIDE + (cc >> 3) * (DD * 8) + row * 8 + (cc & 7);
            if (c < CDIM) kxb[dst] = bfv;
            else          vxb[dst] = bfv;
          }
        }
      }
  }
}

// Fused x-line attention + output projection (proven R11 body; proj B-frags
// now from ppack, coalesced). OOB window slots (reference zero-pads k/v
// AFTER bias): logit 0 counted in softmax denominator -> init m=0, s=noob.
__global__ __launch_bounds__(256, 3) void attn3d_proj(
    const unsigned short* __restrict__ q,     // [vox][192]
    const unsigned short* __restrict__ kx,    // [784][24][28][8]
    const unsigned short* __restrict__ vx,    // [784][24][28][8]
    const unsigned short* __restrict__ ppack, // [12][6][64][8]
    const float* __restrict__ bp,             // [192]
    float* __restrict__ C)                    // [vox][192] fp32
{
  __shared__ __align__(16) unsigned short ytile[32 * 200];

  const int bid = blockIdx.x;
  const int zy = (bid & 7) * 98 + (bid >> 3);   // XCD z-slab swizzle, bijective
  const int z = zy / 28, yr = zy % 28;
  const int h = threadIdx.x >> 6;
  const int lane = threadIdx.x & 63;
  const int x = lane & 31;
  const int xc = x < 28 ? x : 27;               // clamp idle lanes
  const int g = lane >> 5;
  const int cb = h * 48 + g * 24;
  const int cgb = h * 6 + g * 3;
  const int vox = zy * 28 + xc;

  if (threadIdx.x < 100)   // zero M-pad rows 28..31
    *(uint4*)(&ytile[28 * 200 + threadIdx.x * 8]) = make_uint4(0, 0, 0, 0);

  float qf[24];
  {
    const uint4* qp = (const uint4*)(q + (size_t)vox * CDIM + cb);
    const uint4 a = qp[0], b = qp[1], c = qp[2];
    const unsigned int uu[12] = {a.x, a.y, a.z, a.w, b.x, b.y, b.z, b.w,
                                 c.x, c.y, c.z, c.w};
#pragma unroll
    for (int i = 0; i < 12; ++i) { qf[2*i] = blo(uu[i]); qf[2*i+1] = bhi(uu[i]); }
  }

  const int nx = 3 - (x == 0) - (x == 27);
  const int ny = 3 - (yr == 0) - (yr == 27);
  const int nz = 3 - (z == 0) - (z == 27);
  const int noob = 27 - nx * ny * nz;
  float m = noob ? 0.f : -INFINITY;
  float s = (float)noob;
  float out[24];
#pragma unroll
  for (int i = 0; i < 24; ++i) out[i] = 0.f;

  const bool okm = (x > 0), okp = (x < 27);
  const int xm = okm ? xc - 1 : 0;
  const int xp = okp ? xc + 1 : 27;
  int offm[3], offc[3], offp[3];
#pragma unroll
  for (int i = 0; i < 3; ++i) {
    const int ub = (cgb + i) * (DD * 8);
    offm[i] = ub + xm * 8; offc[i] = ub + xc * 8; offp[i] = ub + xp * 8;
  }

  for (int dz = -1; dz <= 1; ++dz) {
    const int zz = z + dz;
    if ((unsigned)zz >= 28u) continue;          // block-uniform
    for (int dy = -1; dy <= 1; ++dy) {
      const int yv = yr + dy;
      if ((unsigned)yv >= 28u) continue;        // block-uniform
      const size_t lbase = (size_t)(zz * 28 + yv) * LSTRIDE;
      const unsigned short* kl = kx + lbase;
      const unsigned short* vl = vx + lbase;

      const uint4 Km0 = *(const uint4*)(kl + offm[0]);
      const uint4 Km1 = *(const uint4*)(kl + offm[1]);
      const uint4 Km2 = *(const uint4*)(kl + offm[2]);
      const uint4 Kc0 = *(const uint4*)(kl + offc[0]);
      const uint4 Kc1 = *(const uint4*)(kl + offc[1]);
      const uint4 Kc2 = *(const uint4*)(kl + offc[2]);
      const uint4 Kp0 = *(const uint4*)(kl + offp[0]);
      const uint4 Kp1 = *(const uint4*)(kl + offp[1]);
      const uint4 Kp2 = *(const uint4*)(kl + offp[2]);
      const unsigned int km[12] = {Km0.x, Km0.y, Km0.z, Km0.w, Km1.x, Km1.y,
                                   Km1.z, Km1.w, Km2.x, Km2.y, Km2.z, Km2.w};
      const unsigned int kc[12] = {Kc0.x, Kc0.y, Kc0.z, Kc0.w, Kc1.x, Kc1.y,
                                   Kc1.z, Kc1.w, Kc2.x, Kc2.y, Kc2.z, Kc2.w};
      const unsigned int kp[12] = {Kp0.x, Kp0.y, Kp0.z, Kp0.w, Kp1.x, Kp1.y,
                                   Kp1.z, Kp1.w, Kp2.x, Kp2.y, Kp2.z, Kp2.w};
      float p0 = 0.f, p1 = 0.f, p2 = 0.f;
#pragma unroll
      for (int i = 0; i < 12; ++i) {
        p0 += qf[2*i] * blo(km[i]) + qf[2*i+1] * bhi(km[i]);
        p1 += qf[2*i] * blo(kc[i]) + qf[2*i+1] * bhi(kc[i]);
        p2 += qf[2*i] * blo(kp[i]) + qf[2*i+1] * bhi(kp[i]);
      }
      p0 += __shfl_xor(p0, 32);   // combine half-head partials
      p1 += __shfl_xor(p1, 32);
      p2 += __shfl_xor(p2, 32);

      // issue V loads before softmax (latency overlap)
      const uint4 Vm0 = *(const uint4*)(vl + offm[0]);
      const uint4 Vm1 = *(const uint4*)(vl + offm[1]);
      const uint4 Vm2 = *(const uint4*)(vl + offm[2]);
      const uint4 Vc0 = *(const uint4*)(vl + offc[0]);
      const uint4 Vc1 = *(const uint4*)(vl + offc[1]);
      const uint4 Vc2 = *(const uint4*)(vl + offc[2]);
      const uint4 Vp0 = *(const uint4*)(vl + offp[0]);
      const uint4 Vp1 = *(const uint4*)(vl + offp[1]);
      const uint4 Vp2 = *(const uint4*)(vl + offp[2]);

      const float l0 = okm ? p0 : -INFINITY;
      const float l2 = okp ? p2 : -INFINITY;
      const float nm = fmaxf(m, fmaxf(p1, fmaxf(l0, l2)));
      const float sc = __expf(m - nm);
      const float w0 = okm ? __expf(p0 - nm) : 0.f;
      const float w1 = __expf(p1 - nm);
      const float w2 = okp ? __expf(p2 - nm) : 0.f;
      s = s * sc + w0 + w1 + w2;
      m = nm;

      const unsigned int vm[12] = {Vm0.x, Vm0.y, Vm0.z, Vm0.w, Vm1.x, Vm1.y,
                                   Vm1.z, Vm1.w, Vm2.x, Vm2.y, Vm2.z, Vm2.w};
      const unsigned int vc[12] = {Vc0.x, Vc0.y, Vc0.z, Vc0.w, Vc1.x, Vc1.y,
                                   Vc1.z, Vc1.w, Vc2.x, Vc2.y, Vc2.z, Vc2.w};
      const unsigned int vp[12] = {Vp0.x, Vp0.y, Vp0.z, Vp0.w, Vp1.x, Vp1.y,
                                   Vp1.z, Vp1.w, Vp2.x, Vp2.y, Vp2.z, Vp2.w};
#pragma unroll
      for (int i = 0; i < 12; ++i) {
        out[2*i]   = out[2*i]   * sc + w0 * blo(vm[i]) + w1 * blo(vc[i]) + w2 * blo(vp[i]);
        out[2*i+1] = out[2*i+1] * sc + w0 * bhi(vm[i]) + w1 * bhi(vc[i]) + w2 * bhi(vp[i]);
      }
    }
  }

  // y-tile to LDS (bf16)
  if (x < 28) {
    const float inv = 1.f / s;
    unsigned int ou[12];
#pragma unroll
    for (int i = 0; i < 12; ++i)
      ou[i] = pk2(out[2*i] * inv, out[2*i+1] * inv);
    uint4* yp = (uint4*)(&ytile[xc * 200 + cb]);
    yp[0] = make_uint4(ou[0], ou[1], ou[2], ou[3]);
    yp[1] = make_uint4(ou[4], ou[5], ou[6], ou[7]);
    yp[2] = make_uint4(ou[8], ou[9], ou[10], ou[11]);
  }
  __syncthreads();

  // projection: C[28x192] = y @ Wp^T + bp, B-frags from ppack
  const int w = threadIdx.x >> 6;
  const int lr = lane & 15, lk = (lane >> 4) * 8;

  f32x4 acc[2][3] = {};
#pragma unroll
  for (int ks = 0; ks < 6; ++ks) {
    const bf16x8 a0 = *(const bf16x8*)(&ytile[lr * 200 + ks * 32 + lk]);
    const bf16x8 a1 = *(const bf16x8*)(&ytile[(16 + lr) * 200 + ks * 32 + lk]);
#pragma unroll
    for (int nj = 0; nj < 3; ++nj) {
      const int ngp = w * 3 + nj;
      const bf16x8 b = *(const bf16x8*)(&ppack[((ngp * 6 + ks) * 64 + lane) * 8]);
      acc[0][nj] = __builtin_amdgcn_mfma_f32_16x16x32_bf16(a0, b, acc[0][nj], 0, 0, 0);
      acc[1][nj] = __builtin_amdgcn_mfma_f32_16x16x32_bf16(a1, b, acc[1][nj], 0, 0, 0);
    }
  }
#pragma unroll
  for (int nj = 0; nj < 3; ++nj) {
    const int gc = w * 48 + nj * 16 + lr;
    const float bv = bp[gc];
#pragma unroll
    for (int mi = 0; mi < 2; ++mi)
#pragma unroll
      for (int rr = 0; rr < 4; ++rr) {
        const int row = mi * 16 + (lane >> 4) * 4 + rr;
        if (row < 28)
          C[(size_t)(zy * 28 + row) * CDIM + gc] = acc[mi][nj][rr] + bv;
      }
  }
}

extern "C" void kernel_launch(void* const* d_in, const int* in_sizes, int n_in,
                              void* d_out, int out_size, void* d_ws, size_t ws_size,
                              hipStream_t stream) {
  const float* x   = (const float*)d_in[0];
  const float* Wq  = (const float*)d_in[1];
  const float* bq  = (const float*)d_in[2];
  const float* Wkv = (const float*)d_in[3];
  const float* bkv = (const float*)d_in[4];
  const float* Wp  = (const float*)d_in[5];
  const float* bp  = (const float*)d_in[6];
  float* out = (float*)d_out;

  unsigned short* wpack = (unsigned short*)d_ws;            // 110592
  unsigned short* ppack = wpack + 110592;                   // 36864
  float*          biasA = (float*)(ppack + 36864);          // 576 floats
  unsigned short* qb    = (unsigned short*)(biasA + 576);   // NVOX*192
  unsigned short* kxb   = qb + (size_t)NVOX * CDIM;         // 784*5376
  unsigned short* vxb   = kxb + (size_t)NLINE * LSTRIDE;    // 784*5376

  prep_pack<<<579, 256, 0, stream>>>(Wq, bq, Wkv, bkv, Wp, wpack, ppack, biasA);
  qkv_line<<<NLINE, 256, 0, stream>>>(x, wpack, biasA, qb, kxb, vxb);
  attn3d_proj<<<NLINE, 256, 0, stream>>>(qb, kxb, vxb, ppack, bp, out);
}

// Round 14
// 134.026 us; speedup vs baseline: 1.4215x; 1.0188x over previous
//
#include <hip/hip_runtime.h>
#include <hip/hip_bf16.h>
#include <math.h>

#define CDIM 192
#define DD 28
#define NVOX (DD * DD * DD)   // 21952
#define NLINE (DD * DD)       // 784
#define LSTRIDE (24 * DD * 8) // 5376 ushorts per kv line
#define LSTR 200              // LDS A-tile row stride (ushorts)
#define SSTR 36               // stg row stride (ushorts): 72B -> 8B-aligned b64, 16-bank spread
#define SCALE 0.14433756729740643f  // 48^-0.5

typedef __attribute__((ext_vector_type(8))) short bf16x8;
typedef __attribute__((ext_vector_type(4))) float f32x4;

__device__ __forceinline__ float blo(unsigned int u) {
  union { unsigned int i; float f; } w; w.i = u << 16; return w.f;
}
__device__ __forceinline__ float bhi(unsigned int u) {
  union { unsigned int i; float f; } w; w.i = u & 0xffff0000u; return w.f;
}
__device__ __forceinline__ unsigned short f2bf(float f) {
  union { float ff; unsigned int i; } w; w.ff = f;
  unsigned int x = w.i;
  return (unsigned short)((x + 0x7fffu + ((x >> 16) & 1u)) >> 16);  // RNE
}
__device__ __forceinline__ unsigned int pk2(float lo, float hi) {
  __hip_bfloat162 h = __float22bfloat162_rn(make_float2(lo, hi));
  union { __hip_bfloat162 h2; unsigned int u; } cv; cv.h2 = h; return cv.u;
}

// Pack weights into MFMA B-fragment order:
// wpack[ng][ks][lane][e]: n = ng*16+(lane&15), k = ks*32+(lane>>4)*8+e.
__global__ __launch_bounds__(256) void prep_pack(
    const float* __restrict__ Wq, const float* __restrict__ bq,
    const float* __restrict__ Wkv, const float* __restrict__ bkv,
    const float* __restrict__ Wp,
    unsigned short* __restrict__ wpack,  // [36][6][64][8]
    unsigned short* __restrict__ ppack,  // [12][6][64][8]
    float* __restrict__ biasA)           // [576]
{
  int t = blockIdx.x * 256 + threadIdx.x;
  if (t < 110592) {
    const int e = t & 7, ln = (t >> 3) & 63;
    const int ks = (t >> 9) % 6, ng = (t >> 9) / 6;
    const int n = ng * 16 + (ln & 15);
    const int k = ks * 32 + (ln >> 4) * 8 + e;
    const float v = (n < CDIM) ? Wq[k * CDIM + n] * SCALE
                               : Wkv[k * 2 * CDIM + (n - CDIM)];
    wpack[t] = f2bf(v);
  } else if (t < 147456) {
    const int u = t - 110592;
    const int e = u & 7, ln = (u >> 3) & 63;
    const int ks = (u >> 9) % 6, ng = (u >> 9) / 6;
    const int n = ng * 16 + (ln & 15);
    const int k = ks * 32 + (ln >> 4) * 8 + e;
    ppack[u] = f2bf(Wp[k * CDIM + n]);
  } else if (t < 148032) {
    const int u = t - 147456;
    biasA[u] = (u < CDIM) ? bq[u] * SCALE : bkv[u - CDIM];
  }
}

// Per-line QKV GEMM: block = line (z,y). x-line staged ONCE to LDS (bf16),
// B-frags coalesced from wpack. k/v epilogue staged via n-major LDS
// (ds_write_b64 per 4-row group) then written out as coalesced uint4 in the
// x-interleaved layout; q written direct (4-segment scatter, acceptable).
__global__ __launch_bounds__(256, 4) void qkv_line(
    const float* __restrict__ X,            // [NVOX][192] fp32
    const unsigned short* __restrict__ wpack,
    const float* __restrict__ biasA,
    unsigned short* __restrict__ qb,        // [vox][192]
    unsigned short* __restrict__ kxb,       // [784][24][28][8]
    unsigned short* __restrict__ vxb)       // [784][24][28][8]
{
  __shared__ __align__(16) unsigned short As[32 * LSTR];    // 12.8 KB
  __shared__ __align__(16) unsigned short stg[384 * SSTR];  // 27.6 KB, n-major
  const int tid = threadIdx.x;
  const int zy = blockIdx.x;

  for (int u = tid; u < 672; u += 256) {   // 28 rows x 24 8-float units
    const int row = u / 24, c = (u % 24) * 8;
    const float4 f0 = *(const float4*)(&X[(size_t)(zy * 28 + row) * CDIM + c]);
    const float4 f1 = *(const float4*)(&X[(size_t)(zy * 28 + row) * CDIM + c + 4]);
    unsigned int o[4] = {pk2(f0.x, f0.y), pk2(f0.z, f0.w),
                         pk2(f1.x, f1.y), pk2(f1.z, f1.w)};
    *(uint4*)(&As[row * LSTR + c]) = *(const uint4*)o;
  }
  for (int u = tid; u < 96; u += 256) {    // zero pad rows 28..31
    const int row = 28 + u / 24, c = (u % 24) * 8;
    *(uint4*)(&As[row * LSTR + c]) = make_uint4(0, 0, 0, 0);
  }
  __syncthreads();

  const int w = tid >> 6;
  const int lane = tid & 63;
  const int lr = lane & 15, lk = (lane >> 4) * 8;

  f32x4 acc[2][9] = {};
#pragma unroll
  for (int ks = 0; ks < 6; ++ks) {
    const bf16x8 a0 = *(const bf16x8*)(&As[lr * LSTR + ks * 32 + lk]);
    const bf16x8 a1 = *(const bf16x8*)(&As[(16 + lr) * LSTR + ks * 32 + lk]);
#pragma unroll
    for (int j = 0; j < 9; ++j) {
      const int ng = w * 9 + j;
      const bf16x8 b = *(const bf16x8*)(&wpack[((ng * 6 + ks) * 64 + lane) * 8]);
      acc[0][j] = __builtin_amdgcn_mfma_f32_16x16x32_bf16(a0, b, acc[0][j], 0, 0, 0);
      acc[1][j] = __builtin_amdgcn_mfma_f32_16x16x32_bf16(a1, b, acc[1][j], 0, 0, 0);
    }
  }

  // C/D: col = lane&15 (-> channel n), row = (lane>>4)*4 + r (-> x)
  const int rb4 = (lane >> 4) * 4;
#pragma unroll
  for (int j = 0; j < 9; ++j) {
    const int n = (w * 9 + j) * 16 + lr;
    const float bv = biasA[n];
    if (n < CDIM) {               // q: direct scalar stores (wave-uniform per j)
#pragma unroll
      for (int mi = 0; mi < 2; ++mi)
#pragma unroll
        for (int rr = 0; rr < 4; ++rr) {
          const int row = mi * 16 + rb4 + rr;
          if (row < 28)
            qb[(size_t)(zy * 28 + row) * CDIM + n] = f2bf(acc[mi][j][rr] + bv);
        }
    } else {                      // k/v: n-major LDS stage, b64 per 4-row group
      const int np = n - CDIM;    // 0..383
#pragma unroll
      for (int mi = 0; mi < 2; ++mi) {
        const unsigned int u0 = pk2(acc[mi][j][0] + bv, acc[mi][j][1] + bv);
        const unsigned int u1 = pk2(acc[mi][j][2] + bv, acc[mi][j][3] + bv);
        *(uint2*)(&stg[np * SSTR + mi * 16 + rb4]) = make_uint2(u0, u1);
      }
    }
  }
  __syncthreads();

  // coalesced writeout: unit = (tensor, cg, x) -> uint4
  for (int u = tid; u < 1344; u += 256) {
    const int t2 = u / 672;                // 0 = k, 1 = v
    const int r = u % 672;
    const int cg = r / 28, x = r % 28;
    const int npb = t2 * CDIM + cg * 8;
    unsigned short tmp[8];
#pragma unroll
    for (int i = 0; i < 8; ++i) tmp[i] = stg[(npb + i) * SSTR + x];
    unsigned short* dst = (t2 ? vxb : kxb) + (size_t)zy * LSTRIDE + cg * 224 + x * 8;
    *(uint4*)dst = *(const uint4*)tmp;
  }
}

// Fused x-line attention + output projection (proven body). OOB window slots
// (reference zero-pads k/v AFTER bias): logit 0 counted in softmax
// denominator -> init m=0, s=noob.
__global__ __launch_bounds__(256, 3) void attn3d_proj(
    const unsigned short* __restrict__ q,     // [vox][192]
    const unsigned short* __restrict__ kx,    // [784][24][28][8]
    const unsigned short* __restrict__ vx,    // [784][24][28][8]
    const unsigned short* __restrict__ ppack, // [12][6][64][8]
    const float* __restrict__ bp,             // [192]
    float* __restrict__ C)                    // [vox][192] fp32
{
  __shared__ __align__(16) unsigned short ytile[32 * 200];

  const int bid = blockIdx.x;
  const int zy = (bid & 7) * 98 + (bid >> 3);   // XCD z-slab swizzle, bijective
  const int z = zy / 28, yr = zy % 28;
  const int h = threadIdx.x >> 6;
  const int lane = threadIdx.x & 63;
  const int x = lane & 31;
  const int xc = x < 28 ? x : 27;               // clamp idle lanes
  const int g = lane >> 5;
  const int cb = h * 48 + g * 24;
  const int cgb = h * 6 + g * 3;
  const int vox = zy * 28 + xc;

  if (threadIdx.x < 100)   // zero M-pad rows 28..31
    *(uint4*)(&ytile[28 * 200 + threadIdx.x * 8]) = make_uint4(0, 0, 0, 0);

  float qf[24];
  {
    const uint4* qp = (const uint4*)(q + (size_t)vox * CDIM + cb);
    const uint4 a = qp[0], b = qp[1], c = qp[2];
    const unsigned int uu[12] = {a.x, a.y, a.z, a.w, b.x, b.y, b.z, b.w,
                                 c.x, c.y, c.z, c.w};
#pragma unroll
    for (int i = 0; i < 12; ++i) { qf[2*i] = blo(uu[i]); qf[2*i+1] = bhi(uu[i]); }
  }

  const int nx = 3 - (x == 0) - (x == 27);
  const int ny = 3 - (yr == 0) - (yr == 27);
  const int nz = 3 - (z == 0) - (z == 27);
  const int noob = 27 - nx * ny * nz;
  float m = noob ? 0.f : -INFINITY;
  float s = (float)noob;
  float out[24];
#pragma unroll
  for (int i = 0; i < 24; ++i) out[i] = 0.f;

  const bool okm = (x > 0), okp = (x < 27);
  const int xm = okm ? xc - 1 : 0;
  const int xp = okp ? xc + 1 : 27;
  int offm[3], offc[3], offp[3];
#pragma unroll
  for (int i = 0; i < 3; ++i) {
    const int ub = (cgb + i) * (DD * 8);
    offm[i] = ub + xm * 8; offc[i] = ub + xc * 8; offp[i] = ub + xp * 8;
  }

  for (int dz = -1; dz <= 1; ++dz) {
    const int zz = z + dz;
    if ((unsigned)zz >= 28u) continue;          // block-uniform
    for (int dy = -1; dy <= 1; ++dy) {
      const int yv = yr + dy;
      if ((unsigned)yv >= 28u) continue;        // block-uniform
      const size_t lbase = (size_t)(zz * 28 + yv) * LSTRIDE;
      const unsigned short* kl = kx + lbase;
      const unsigned short* vl = vx + lbase;

      const uint4 Km0 = *(const uint4*)(kl + offm[0]);
      const uint4 Km1 = *(const uint4*)(kl + offm[1]);
      const uint4 Km2 = *(const uint4*)(kl + offm[2]);
      const uint4 Kc0 = *(const uint4*)(kl + offc[0]);
      const uint4 Kc1 = *(const uint4*)(kl + offc[1]);
      const uint4 Kc2 = *(const uint4*)(kl + offc[2]);
      const uint4 Kp0 = *(const uint4*)(kl + offp[0]);
      const uint4 Kp1 = *(const uint4*)(kl + offp[1]);
      const uint4 Kp2 = *(const uint4*)(kl + offp[2]);
      const unsigned int km[12] = {Km0.x, Km0.y, Km0.z, Km0.w, Km1.x, Km1.y,
                                   Km1.z, Km1.w, Km2.x, Km2.y, Km2.z, Km2.w};
      const unsigned int kc[12] = {Kc0.x, Kc0.y, Kc0.z, Kc0.w, Kc1.x, Kc1.y,
                                   Kc1.z, Kc1.w, Kc2.x, Kc2.y, Kc2.z, Kc2.w};
      const unsigned int kp[12] = {Kp0.x, Kp0.y, Kp0.z, Kp0.w, Kp1.x, Kp1.y,
                                   Kp1.z, Kp1.w, Kp2.x, Kp2.y, Kp2.z, Kp2.w};
      float p0 = 0.f, p1 = 0.f, p2 = 0.f;
#pragma unroll
      for (int i = 0; i < 12; ++i) {
        p0 += qf[2*i] * blo(km[i]) + qf[2*i+1] * bhi(km[i]);
        p1 += qf[2*i] * blo(kc[i]) + qf[2*i+1] * bhi(kc[i]);
        p2 += qf[2*i] * blo(kp[i]) + qf[2*i+1] * bhi(kp[i]);
      }
      p0 += __shfl_xor(p0, 32);   // combine half-head partials
      p1 += __shfl_xor(p1, 32);
      p2 += __shfl_xor(p2, 32);

      // issue V loads before softmax (latency overlap)
      const uint4 Vm0 = *(const uint4*)(vl + offm[0]);
      const uint4 Vm1 = *(const uint4*)(vl + offm[1]);
      const uint4 Vm2 = *(const uint4*)(vl + offm[2]);
      const uint4 Vc0 = *(const uint4*)(vl + offc[0]);
      const uint4 Vc1 = *(const uint4*)(vl + offc[1]);
      const uint4 Vc2 = *(const uint4*)(vl + offc[2]);
      const uint4 Vp0 = *(const uint4*)(vl + offp[0]);
      const uint4 Vp1 = *(const uint4*)(vl + offp[1]);
      const uint4 Vp2 = *(const uint4*)(vl + offp[2]);

      const float l0 = okm ? p0 : -INFINITY;
      const float l2 = okp ? p2 : -INFINITY;
      const float nm = fmaxf(m, fmaxf(p1, fmaxf(l0, l2)));
      const float sc = __expf(m - nm);
      const float w0 = okm ? __expf(p0 - nm) : 0.f;
      const float w1 = __expf(p1 - nm);
      const float w2 = okp ? __expf(p2 - nm) : 0.f;
      s = s * sc + w0 + w1 + w2;
      m = nm;

      const unsigned int vm[12] = {Vm0.x, Vm0.y, Vm0.z, Vm0.w, Vm1.x, Vm1.y,
                                   Vm1.z, Vm1.w, Vm2.x, Vm2.y, Vm2.z, Vm2.w};
      const unsigned int vc[12] = {Vc0.x, Vc0.y, Vc0.z, Vc0.w, Vc1.x, Vc1.y,
                                   Vc1.z, Vc1.w, Vc2.x, Vc2.y, Vc2.z, Vc2.w};
      const unsigned int vp[12] = {Vp0.x, Vp0.y, Vp0.z, Vp0.w, Vp1.x, Vp1.y,
                                   Vp1.z, Vp1.w, Vp2.x, Vp2.y, Vp2.z, Vp2.w};
#pragma unroll
      for (int i = 0; i < 12; ++i) {
        out[2*i]   = out[2*i]   * sc + w0 * blo(vm[i]) + w1 * blo(vc[i]) + w2 * blo(vp[i]);
        out[2*i+1] = out[2*i+1] * sc + w0 * bhi(vm[i]) + w1 * bhi(vc[i]) + w2 * bhi(vp[i]);
      }
    }
  }

  // y-tile to LDS (bf16)
  if (x < 28) {
    const float inv = 1.f / s;
    unsigned int ou[12];
#pragma unroll
    for (int i = 0; i < 12; ++i)
      ou[i] = pk2(out[2*i] * inv, out[2*i+1] * inv);
    uint4* yp = (uint4*)(&ytile[xc * 200 + cb]);
    yp[0] = make_uint4(ou[0], ou[1], ou[2], ou[3]);
    yp[1] = make_uint4(ou[4], ou[5], ou[6], ou[7]);
    yp[2] = make_uint4(ou[8], ou[9], ou[10], ou[11]);
  }
  __syncthreads();

  // projection: C[28x192] = y @ Wp^T + bp, B-frags from ppack
  const int w = threadIdx.x >> 6;
  const int lr = lane & 15, lk = (lane >> 4) * 8;

  f32x4 acc[2][3] = {};
#pragma unroll
  for (int ks = 0; ks < 6; ++ks) {
    const bf16x8 a0 = *(const bf16x8*)(&ytile[lr * 200 + ks * 32 + lk]);
    const bf16x8 a1 = *(const bf16x8*)(&ytile[(16 + lr) * 200 + ks * 32 + lk]);
#pragma unroll
    for (int nj = 0; nj < 3; ++nj) {
      const int ngp = w * 3 + nj;
      const bf16x8 b = *(const bf16x8*)(&ppack[((ngp * 6 + ks) * 64 + lane) * 8]);
      acc[0][nj] = __builtin_amdgcn_mfma_f32_16x16x32_bf16(a0, b, acc[0][nj], 0, 0, 0);
      acc[1][nj] = __builtin_amdgcn_mfma_f32_16x16x32_bf16(a1, b, acc[1][nj], 0, 0, 0);
    }
  }
#pragma unroll
  for (int nj = 0; nj < 3; ++nj) {
    const int gc = w * 48 + nj * 16 + lr;
    const float bv = bp[gc];
#pragma unroll
    for (int mi = 0; mi < 2; ++mi)
#pragma unroll
      for (int rr = 0; rr < 4; ++rr) {
        const int row = mi * 16 + (lane >> 4) * 4 + rr;
        if (row < 28)
          C[(size_t)(zy * 28 + row) * CDIM + gc] = acc[mi][nj][rr] + bv;
      }
  }
}

extern "C" void kernel_launch(void* const* d_in, const int* in_sizes, int n_in,
                              void* d_out, int out_size, void* d_ws, size_t ws_size,
                              hipStream_t stream) {
  const float* x   = (const float*)d_in[0];
  const float* Wq  = (const float*)d_in[1];
  const float* bq  = (const float*)d_in[2];
  const float* Wkv = (const float*)d_in[3];
  const float* bkv = (const float*)d_in[4];
  const float* Wp  = (const float*)d_in[5];
  const float* bp  = (const float*)d_in[6];
  float* out = (float*)d_out;

  unsigned short* wpack = (unsigned short*)d_ws;            // 110592
  unsigned short* ppack = wpack + 110592;                   // 36864
  float*          biasA = (float*)(ppack + 36864);          // 576 floats
  unsigned short* qb    = (unsigned short*)(biasA + 576);   // NVOX*192
  unsigned short* kxb   = qb + (size_t)NVOX * CDIM;         // 784*5376
  unsigned short* vxb   = kxb + (size_t)NLINE * LSTRIDE;    // 784*5376

  prep_pack<<<579, 256, 0, stream>>>(Wq, bq, Wkv, bkv, Wp, wpack, ppack, biasA);
  qkv_line<<<NLINE, 256, 0, stream>>>(x, wpack, biasA, qb, kxb, vxb);
  attn3d_proj<<<NLINE, 256, 0, stream>>>(qb, kxb, vxb, ppack, bp, out);
}